// Round 1
// baseline (3296.307 us; speedup 1.0000x reference)
//
#include <hip/hip_runtime.h>

#define NN 50000
#define NE 600000
#define D 128
#define DOUT3 47
#define BN_EPS 1e-5f

__global__ void zero_kernel(float4* __restrict__ p, long n4) {
  long i = (long)blockIdx.x * blockDim.x + threadIdx.x;
  long stride = (long)gridDim.x * blockDim.x;
  for (; i < n4; i += stride) p[i] = make_float4(0.f, 0.f, 0.f, 0.f);
}

__global__ void count_kernel(const int* __restrict__ dst, float* __restrict__ cnt, int E) {
  int t = blockIdx.x * blockDim.x + threadIdx.x;
  if (t < E) {
    int d = dst[t];
    d = max(0, min(NN - 1, d));  // defensive clamp
    atomicAdd(&cnt[d], 1.0f);
  }
}

// 32 threads per edge; each thread moves one float4 (4 floats) of the 128-dim row.
__global__ void scatter_kernel(const float* __restrict__ feat, const int* __restrict__ src,
                               const int* __restrict__ dst, float* __restrict__ agg, int E) {
  int t = blockIdx.x * blockDim.x + threadIdx.x;
  int e = t >> 5;
  int c = (t & 31) << 2;
  if (e >= E) return;
  int s = src[e], d = dst[e];
  s = max(0, min(NN - 1, s));  // defensive clamp
  d = max(0, min(NN - 1, d));
  float4 v = *(const float4*)(feat + (long)s * D + c);
  float* p = agg + (long)d * D + c;
  atomicAdd(p + 0, v.x);
  atomicAdd(p + 1, v.y);
  atomicAdd(p + 2, v.z);
  atomicAdd(p + 3, v.w);
}

// out[row, j] = relu(bn( (agg[row]/max(cnt,1)) @ Wl + b + xin[row] @ Wr ))
// Block: NT threads (thread j = output column), R=16 rows staged in LDS.
template <int DOUT, int NT, bool BN>
__global__ __launch_bounds__(NT) void fused_layer(
    const float* __restrict__ agg, const float* __restrict__ cnt,
    const float* __restrict__ xin,
    const float* __restrict__ Wl, const float* __restrict__ bias,
    const float* __restrict__ Wr,
    const float* __restrict__ g, const float* __restrict__ be,
    const float* __restrict__ m, const float* __restrict__ v,
    float* __restrict__ out, int ldo) {
  const int R = 16;
  __shared__ float s_a[R][D];
  __shared__ float s_x[R][D];
  int row0 = blockIdx.x * R;
  int tid = threadIdx.x;

  for (int idx = tid; idx < R * D; idx += NT) {
    int r = idx >> 7;
    int k = idx & (D - 1);
    int row = row0 + r;
    float c = cnt[row];
    float iv = 1.0f / fmaxf(c, 1.0f);
    s_a[r][k] = agg[(long)row * D + k] * iv;
    s_x[r][k] = xin[(long)row * D + k];
  }
  __syncthreads();

  int j = tid;
  int jj = j < DOUT ? j : DOUT - 1;
  float acc[R];
  float bj = bias[jj];
#pragma unroll
  for (int r = 0; r < R; r++) acc[r] = bj;

  for (int k = 0; k < D; k += 4) {
    float wl0 = Wl[(k + 0) * DOUT + jj], wl1 = Wl[(k + 1) * DOUT + jj];
    float wl2 = Wl[(k + 2) * DOUT + jj], wl3 = Wl[(k + 3) * DOUT + jj];
    float wr0 = Wr[(k + 0) * DOUT + jj], wr1 = Wr[(k + 1) * DOUT + jj];
    float wr2 = Wr[(k + 2) * DOUT + jj], wr3 = Wr[(k + 3) * DOUT + jj];
#pragma unroll
    for (int r = 0; r < R; r++) {
      const float4 a = *(const float4*)&s_a[r][k];
      const float4 x = *(const float4*)&s_x[r][k];
      float t = acc[r];
      t = fmaf(a.x, wl0, t); t = fmaf(a.y, wl1, t);
      t = fmaf(a.z, wl2, t); t = fmaf(a.w, wl3, t);
      t = fmaf(x.x, wr0, t); t = fmaf(x.y, wr1, t);
      t = fmaf(x.z, wr2, t); t = fmaf(x.w, wr3, t);
      acc[r] = t;
    }
  }

  if (j < DOUT) {
    float sc = 1.f, sh = 0.f;
    if (BN) {
      sc = g[j] * rsqrtf(v[j] + BN_EPS);
      sh = be[j] - m[j] * sc;
    }
#pragma unroll
    for (int r = 0; r < R; r++) {
      float val = acc[r];
      if (BN) {
        val = val * sc + sh;
        val = fmaxf(val, 0.f);
      }
      out[(long)(row0 + r) * ldo + j] = val;
    }
  }
}

extern "C" void kernel_launch(void* const* d_in, const int* in_sizes, int n_in,
                              void* d_out, int out_size, void* d_ws, size_t ws_size,
                              hipStream_t stream) {
  const float* x = (const float*)d_in[0];
  const int* ei = (const int*)d_in[1];
  const int* src = ei;
  const int* dst = ei + NE;
  const float* W1l = (const float*)d_in[2];
  const float* b1  = (const float*)d_in[3];
  const float* W1r = (const float*)d_in[4];
  const float* W2l = (const float*)d_in[5];
  const float* b2  = (const float*)d_in[6];
  const float* W2r = (const float*)d_in[7];
  const float* W3l = (const float*)d_in[8];
  const float* b3  = (const float*)d_in[9];
  const float* W3r = (const float*)d_in[10];
  const float* g1  = (const float*)d_in[11];
  const float* be1 = (const float*)d_in[12];
  const float* m1  = (const float*)d_in[13];
  const float* v1  = (const float*)d_in[14];
  const float* g2  = (const float*)d_in[15];
  const float* be2 = (const float*)d_in[16];
  const float* m2  = (const float*)d_in[17];
  const float* v2  = (const float*)d_in[18];

  float* out = (float*)d_out;

  float* cnt = (float*)d_ws;           // NN floats
  float* agg = cnt + NN;               // NN*D
  float* h1  = agg + (long)NN * D;     // NN*D
  float* h2  = h1 + (long)NN * D;      // NN*D

  const int ZB = 256;
  long n4_all = (long)NN * (D + 1) / 4;  // cnt + agg contiguous
  long n4_agg = (long)NN * D / 4;

  int scatter_blocks = (NE * 32 + 255) / 256;
  int count_blocks = (NE + 255) / 256;
  int gemm_blocks = NN / 16;

  // degree count + zero cnt/agg
  zero_kernel<<<2048, ZB, 0, stream>>>((float4*)d_ws, n4_all);
  count_kernel<<<count_blocks, 256, 0, stream>>>(dst, cnt, NE);

  // layer 1
  scatter_kernel<<<scatter_blocks, 256, 0, stream>>>(x, src, dst, agg, NE);
  fused_layer<D, 128, true><<<gemm_blocks, 128, 0, stream>>>(
      agg, cnt, x, W1l, b1, W1r, g1, be1, m1, v1, h1, D);

  // layer 2
  zero_kernel<<<2048, ZB, 0, stream>>>((float4*)agg, n4_agg);
  scatter_kernel<<<scatter_blocks, 256, 0, stream>>>(h1, src, dst, agg, NE);
  fused_layer<D, 128, true><<<gemm_blocks, 128, 0, stream>>>(
      agg, cnt, h1, W2l, b2, W2r, g2, be2, m2, v2, h2, D);

  // layer 3 (no BN/ReLU)
  zero_kernel<<<2048, ZB, 0, stream>>>((float4*)agg, n4_agg);
  scatter_kernel<<<scatter_blocks, 256, 0, stream>>>(h2, src, dst, agg, NE);
  fused_layer<DOUT3, 64, false><<<gemm_blocks, 64, 0, stream>>>(
      agg, cnt, h2, W3l, b3, W3r, nullptr, nullptr, nullptr, nullptr, out, DOUT3);
}

// Round 2
// 597.512 us; speedup vs baseline: 5.5167x; 5.5167x over previous
//
#include <hip/hip_runtime.h>

#define NN 50000
#define NE 600000
#define D 128
#define DOUT3 47
#define BN_EPS 1e-5f
#define SCAN_T 1024

__global__ void zero_int(int* __restrict__ p, int n) {
  int i = blockIdx.x * blockDim.x + threadIdx.x;
  if (i < n) p[i] = 0;
}

__global__ void hist_kernel(const int* __restrict__ dst, int* __restrict__ deg, int E) {
  int e = blockIdx.x * blockDim.x + threadIdx.x;
  if (e < E) {
    int d = dst[e];
    d = max(0, min(NN - 1, d));
    atomicAdd(&deg[d], 1);
  }
}

// Single-block exclusive scan of deg[0..NN) -> row_start[0..NN], plus cursor copy.
__global__ __launch_bounds__(SCAN_T) void scan_kernel(const int* __restrict__ deg,
                                                      int* __restrict__ row_start,
                                                      int* __restrict__ cursor) {
  __shared__ int s[SCAN_T];
  int t = threadIdx.x;
  const int CH = (NN + SCAN_T - 1) / SCAN_T;  // 49
  int i0 = t * CH;
  int i1 = min(i0 + CH, NN);
  int sum = 0;
  for (int i = i0; i < i1; i++) sum += deg[i];
  s[t] = sum;
  __syncthreads();
  for (int off = 1; off < SCAN_T; off <<= 1) {
    int v = (t >= off) ? s[t - off] : 0;
    __syncthreads();
    s[t] += v;
    __syncthreads();
  }
  int run = s[t] - sum;  // exclusive base for this thread's chunk
  for (int i = i0; i < i1; i++) {
    row_start[i] = run;
    cursor[i] = run;
    run += deg[i];
  }
  if (t == SCAN_T - 1) row_start[NN] = NE;
}

__global__ void build_kernel(const int* __restrict__ src, const int* __restrict__ dst,
                             int* __restrict__ cursor, int* __restrict__ srcs, int E) {
  int e = blockIdx.x * blockDim.x + threadIdx.x;
  if (e < E) {
    int d = dst[e];
    d = max(0, min(NN - 1, d));
    int s = src[e];
    s = max(0, min(NN - 1, s));
    int pos = atomicAdd(&cursor[d], 1);
    srcs[pos] = s;
  }
}

// One 64-lane wave per node; lane handles 2 columns (float2 = 8B -> 512B/wave/row).
__global__ __launch_bounds__(256) void gather_mean(const float* __restrict__ feat,
                                                   const int* __restrict__ row_start,
                                                   const int* __restrict__ srcs,
                                                   float* __restrict__ agg) {
  int node = (blockIdx.x * blockDim.x + threadIdx.x) >> 6;
  int lane = threadIdx.x & 63;
  if (node >= NN) return;
  int start = row_start[node], end = row_start[node + 1];
  float ax = 0.f, ay = 0.f;
  for (int j = start; j < end; j++) {
    int s = srcs[j];
    const float2 v = *(const float2*)(feat + (long)s * D + lane * 2);
    ax += v.x;
    ay += v.y;
  }
  float iv = 1.0f / fmaxf((float)(end - start), 1.0f);
  *(float2*)(agg + (long)node * D + lane * 2) = make_float2(ax * iv, ay * iv);
}

// out[row, j] = maybe_relu_bn( agg[row] @ Wl + b + xin[row] @ Wr )
// agg is already mean-divided. Safe to have out alias xin (rows staged in LDS first).
template <int DOUT, int NT, bool BN>
__global__ __launch_bounds__(NT) void fused_layer(
    const float* __restrict__ agg, const float* __restrict__ xin,
    const float* __restrict__ Wl, const float* __restrict__ bias,
    const float* __restrict__ Wr,
    const float* __restrict__ g, const float* __restrict__ be,
    const float* __restrict__ m, const float* __restrict__ v,
    float* __restrict__ out, int ldo) {
  const int R = 16;
  __shared__ float s_a[R][D];
  __shared__ float s_x[R][D];
  int row0 = blockIdx.x * R;
  int tid = threadIdx.x;

  for (int idx = tid; idx < R * D; idx += NT) {
    int r = idx >> 7;
    int k = idx & (D - 1);
    int row = row0 + r;
    s_a[r][k] = agg[(long)row * D + k];
    s_x[r][k] = xin[(long)row * D + k];
  }
  __syncthreads();

  int j = tid;
  int jj = j < DOUT ? j : DOUT - 1;
  float acc[R];
  float bj = bias[jj];
#pragma unroll
  for (int r = 0; r < R; r++) acc[r] = bj;

  for (int k = 0; k < D; k += 4) {
    float wl0 = Wl[(k + 0) * DOUT + jj], wl1 = Wl[(k + 1) * DOUT + jj];
    float wl2 = Wl[(k + 2) * DOUT + jj], wl3 = Wl[(k + 3) * DOUT + jj];
    float wr0 = Wr[(k + 0) * DOUT + jj], wr1 = Wr[(k + 1) * DOUT + jj];
    float wr2 = Wr[(k + 2) * DOUT + jj], wr3 = Wr[(k + 3) * DOUT + jj];
#pragma unroll
    for (int r = 0; r < R; r++) {
      const float4 a = *(const float4*)&s_a[r][k];
      const float4 x = *(const float4*)&s_x[r][k];
      float t = acc[r];
      t = fmaf(a.x, wl0, t); t = fmaf(a.y, wl1, t);
      t = fmaf(a.z, wl2, t); t = fmaf(a.w, wl3, t);
      t = fmaf(x.x, wr0, t); t = fmaf(x.y, wr1, t);
      t = fmaf(x.z, wr2, t); t = fmaf(x.w, wr3, t);
      acc[r] = t;
    }
  }
  __syncthreads();  // ensure all reads of xin done before in-place write

  if (j < DOUT) {
    float sc = 1.f, sh = 0.f;
    if (BN) {
      sc = g[j] * rsqrtf(v[j] + BN_EPS);
      sh = be[j] - m[j] * sc;
    }
#pragma unroll
    for (int r = 0; r < R; r++) {
      float val = acc[r];
      if (BN) {
        val = val * sc + sh;
        val = fmaxf(val, 0.f);
      }
      out[(long)(row0 + r) * ldo + j] = val;
    }
  }
}

extern "C" void kernel_launch(void* const* d_in, const int* in_sizes, int n_in,
                              void* d_out, int out_size, void* d_ws, size_t ws_size,
                              hipStream_t stream) {
  const float* x = (const float*)d_in[0];
  const int* ei = (const int*)d_in[1];
  const int* src = ei;
  const int* dst = ei + NE;
  const float* W1l = (const float*)d_in[2];
  const float* b1  = (const float*)d_in[3];
  const float* W1r = (const float*)d_in[4];
  const float* W2l = (const float*)d_in[5];
  const float* b2  = (const float*)d_in[6];
  const float* W2r = (const float*)d_in[7];
  const float* W3l = (const float*)d_in[8];
  const float* b3  = (const float*)d_in[9];
  const float* W3r = (const float*)d_in[10];
  const float* g1  = (const float*)d_in[11];
  const float* be1 = (const float*)d_in[12];
  const float* m1  = (const float*)d_in[13];
  const float* v1  = (const float*)d_in[14];
  const float* g2  = (const float*)d_in[15];
  const float* be2 = (const float*)d_in[16];
  const float* m2  = (const float*)d_in[17];
  const float* v2  = (const float*)d_in[18];

  float* out = (float*)d_out;

  // workspace layout (ints then floats)
  int* deg       = (int*)d_ws;            // NN
  int* row_start = deg + NN;              // NN+1
  int* cursor    = row_start + NN + 1;    // NN
  int* srcs      = cursor + NN;           // NE
  float* agg     = (float*)(srcs + NE);   // NN*D
  float* h1      = agg + (long)NN * D;    // NN*D  (reused as layer-2 output in place)

  // ---- CSR build ----
  zero_int<<<(NN + 255) / 256, 256, 0, stream>>>(deg, NN);
  hist_kernel<<<(NE + 255) / 256, 256, 0, stream>>>(dst, deg, NE);
  scan_kernel<<<1, SCAN_T, 0, stream>>>(deg, row_start, cursor);
  build_kernel<<<(NE + 255) / 256, 256, 0, stream>>>(src, dst, cursor, srcs, NE);

  int gather_blocks = (NN * 64 + 255) / 256;  // one wave per node
  int gemm_blocks = NN / 16;                  // 50000 % 16 == 0

  // ---- layer 1 ----
  gather_mean<<<gather_blocks, 256, 0, stream>>>(x, row_start, srcs, agg);
  fused_layer<D, 128, true><<<gemm_blocks, 128, 0, stream>>>(
      agg, x, W1l, b1, W1r, g1, be1, m1, v1, h1, D);

  // ---- layer 2 (output in-place over h1) ----
  gather_mean<<<gather_blocks, 256, 0, stream>>>(h1, row_start, srcs, agg);
  fused_layer<D, 128, true><<<gemm_blocks, 128, 0, stream>>>(
      agg, h1, W2l, b2, W2r, g2, be2, m2, v2, h1, D);

  // ---- layer 3 (no BN/ReLU) ----
  gather_mean<<<gather_blocks, 256, 0, stream>>>(h1, row_start, srcs, agg);
  fused_layer<DOUT3, 64, false><<<gemm_blocks, 64, 0, stream>>>(
      agg, h1, W3l, b3, W3r, nullptr, nullptr, nullptr, nullptr, out, DOUT3);
}

// Round 3
// 500.973 us; speedup vs baseline: 6.5798x; 1.1927x over previous
//
#include <hip/hip_runtime.h>

#define NN 50000
#define NE 600000
#define D 128
#define DOUT3 47
#define BN_EPS 1e-5f
#define NPB 256  // scan elements per block

__global__ void zero_int(int* __restrict__ p, int n) {
  int i = blockIdx.x * blockDim.x + threadIdx.x;
  if (i < n) p[i] = 0;
}

__global__ void hist_kernel(const int* __restrict__ dst, int* __restrict__ deg, int E) {
  int e = blockIdx.x * blockDim.x + threadIdx.x;
  if (e < E) {
    int d = dst[e];
    d = max(0, min(NN - 1, d));
    atomicAdd(&deg[d], 1);
  }
}

// Stage 1: per-block local exclusive scan (NPB elements), emit block totals.
__global__ __launch_bounds__(NPB) void scan_local(const int* __restrict__ deg,
                                                  int* __restrict__ row_start,
                                                  int* __restrict__ partials) {
  __shared__ int s[NPB];
  int t = threadIdx.x;
  int i = blockIdx.x * NPB + t;
  int v = (i < NN) ? deg[i] : 0;
  s[t] = v;
  __syncthreads();
  for (int off = 1; off < NPB; off <<= 1) {
    int u = (t >= off) ? s[t - off] : 0;
    __syncthreads();
    s[t] += u;
    __syncthreads();
  }
  if (i < NN) row_start[i] = s[t] - v;  // local exclusive
  if (t == NPB - 1) partials[blockIdx.x] = s[NPB - 1];
}

// Stage 2: single block, exclusive scan of block totals (nb <= 256).
__global__ __launch_bounds__(256) void scan_partials(int* __restrict__ partials, int nb) {
  __shared__ int s[256];
  int t = threadIdx.x;
  int v = (t < nb) ? partials[t] : 0;
  s[t] = v;
  __syncthreads();
  for (int off = 1; off < 256; off <<= 1) {
    int u = (t >= off) ? s[t - off] : 0;
    __syncthreads();
    s[t] += u;
    __syncthreads();
  }
  if (t < nb) partials[t] = s[t] - v;  // exclusive
}

// Stage 3: add block bases, produce final row_start + cursor copy.
__global__ __launch_bounds__(NPB) void scan_add(int* __restrict__ row_start,
                                                const int* __restrict__ partials,
                                                int* __restrict__ cursor) {
  int i = blockIdx.x * NPB + threadIdx.x;
  if (i < NN) {
    int r = row_start[i] + partials[blockIdx.x];
    row_start[i] = r;
    cursor[i] = r;
  }
  if (i == 0) row_start[NN] = NE;
}

__global__ void build_kernel(const int* __restrict__ src, const int* __restrict__ dst,
                             int* __restrict__ cursor, int* __restrict__ srcs, int E) {
  int e = blockIdx.x * blockDim.x + threadIdx.x;
  if (e < E) {
    int d = dst[e];
    d = max(0, min(NN - 1, d));
    int s = src[e];
    s = max(0, min(NN - 1, s));
    int pos = atomicAdd(&cursor[d], 1);
    srcs[pos] = s;
  }
}

// One 64-lane wave per node; lane handles 2 columns (float2 = 8B -> 512B/wave/row).
__global__ __launch_bounds__(256) void gather_mean(const float* __restrict__ feat,
                                                   const int* __restrict__ row_start,
                                                   const int* __restrict__ srcs,
                                                   float* __restrict__ agg) {
  int node = (blockIdx.x * blockDim.x + threadIdx.x) >> 6;
  int lane = threadIdx.x & 63;
  if (node >= NN) return;
  int start = row_start[node], end = row_start[node + 1];
  float ax = 0.f, ay = 0.f;
  for (int j = start; j < end; j++) {
    int s = srcs[j];
    const float2 v = *(const float2*)(feat + (long)s * D + lane * 2);
    ax += v.x;
    ay += v.y;
  }
  float iv = 1.0f / fmaxf((float)(end - start), 1.0f);
  *(float2*)(agg + (long)node * D + lane * 2) = make_float2(ax * iv, ay * iv);
}

// out[row, j] = maybe_relu_bn( agg[row] @ Wl + b + xin[row] @ Wr )
template <int DOUT, int NT, bool BN>
__global__ __launch_bounds__(NT) void fused_layer(
    const float* __restrict__ agg, const float* __restrict__ xin,
    const float* __restrict__ Wl, const float* __restrict__ bias,
    const float* __restrict__ Wr,
    const float* __restrict__ g, const float* __restrict__ be,
    const float* __restrict__ m, const float* __restrict__ v,
    float* __restrict__ out, int ldo) {
  const int R = 16;
  __shared__ float s_a[R][D];
  __shared__ float s_x[R][D];
  int row0 = blockIdx.x * R;
  int tid = threadIdx.x;

  for (int idx = tid; idx < R * D; idx += NT) {
    int r = idx >> 7;
    int k = idx & (D - 1);
    int row = row0 + r;
    s_a[r][k] = agg[(long)row * D + k];
    s_x[r][k] = xin[(long)row * D + k];
  }
  __syncthreads();

  int j = tid;
  int jj = j < DOUT ? j : DOUT - 1;
  float acc[R];
  float bj = bias[jj];
#pragma unroll
  for (int r = 0; r < R; r++) acc[r] = bj;

  for (int k = 0; k < D; k += 4) {
    float wl0 = Wl[(k + 0) * DOUT + jj], wl1 = Wl[(k + 1) * DOUT + jj];
    float wl2 = Wl[(k + 2) * DOUT + jj], wl3 = Wl[(k + 3) * DOUT + jj];
    float wr0 = Wr[(k + 0) * DOUT + jj], wr1 = Wr[(k + 1) * DOUT + jj];
    float wr2 = Wr[(k + 2) * DOUT + jj], wr3 = Wr[(k + 3) * DOUT + jj];
#pragma unroll
    for (int r = 0; r < R; r++) {
      const float4 a = *(const float4*)&s_a[r][k];
      const float4 x = *(const float4*)&s_x[r][k];
      float t = acc[r];
      t = fmaf(a.x, wl0, t); t = fmaf(a.y, wl1, t);
      t = fmaf(a.z, wl2, t); t = fmaf(a.w, wl3, t);
      t = fmaf(x.x, wr0, t); t = fmaf(x.y, wr1, t);
      t = fmaf(x.z, wr2, t); t = fmaf(x.w, wr3, t);
      acc[r] = t;
    }
  }
  __syncthreads();  // all reads of xin done before potential in-place write

  if (j < DOUT) {
    float sc = 1.f, sh = 0.f;
    if (BN) {
      sc = g[j] * rsqrtf(v[j] + BN_EPS);
      sh = be[j] - m[j] * sc;
    }
#pragma unroll
    for (int r = 0; r < R; r++) {
      float val = acc[r];
      if (BN) {
        val = val * sc + sh;
        val = fmaxf(val, 0.f);
      }
      out[(long)(row0 + r) * ldo + j] = val;
    }
  }
}

extern "C" void kernel_launch(void* const* d_in, const int* in_sizes, int n_in,
                              void* d_out, int out_size, void* d_ws, size_t ws_size,
                              hipStream_t stream) {
  const float* x = (const float*)d_in[0];
  const int* ei = (const int*)d_in[1];
  const int* src = ei;
  const int* dst = ei + NE;
  const float* W1l = (const float*)d_in[2];
  const float* b1  = (const float*)d_in[3];
  const float* W1r = (const float*)d_in[4];
  const float* W2l = (const float*)d_in[5];
  const float* b2  = (const float*)d_in[6];
  const float* W2r = (const float*)d_in[7];
  const float* W3l = (const float*)d_in[8];
  const float* b3  = (const float*)d_in[9];
  const float* W3r = (const float*)d_in[10];
  const float* g1  = (const float*)d_in[11];
  const float* be1 = (const float*)d_in[12];
  const float* m1  = (const float*)d_in[13];
  const float* v1  = (const float*)d_in[14];
  const float* g2  = (const float*)d_in[15];
  const float* be2 = (const float*)d_in[16];
  const float* m2  = (const float*)d_in[17];
  const float* v2  = (const float*)d_in[18];

  float* out = (float*)d_out;

  const int SB = (NN + NPB - 1) / NPB;  // 196 scan blocks

  // workspace layout (ints then floats)
  int* deg       = (int*)d_ws;            // NN
  int* row_start = deg + NN;              // NN+1
  int* cursor    = row_start + NN + 1;    // NN
  int* partials  = cursor + NN;           // SB (<=256)
  int* srcs      = partials + 256;        // NE
  float* agg     = (float*)(srcs + NE);   // NN*D
  float* h1      = agg + (long)NN * D;    // NN*D (layer-2 output in place)

  // ---- CSR build ----
  zero_int<<<(NN + 255) / 256, 256, 0, stream>>>(deg, NN);
  hist_kernel<<<(NE + 255) / 256, 256, 0, stream>>>(dst, deg, NE);
  scan_local<<<SB, NPB, 0, stream>>>(deg, row_start, partials);
  scan_partials<<<1, 256, 0, stream>>>(partials, SB);
  scan_add<<<SB, NPB, 0, stream>>>(row_start, partials, cursor);
  build_kernel<<<(NE + 255) / 256, 256, 0, stream>>>(src, dst, cursor, srcs, NE);

  int gather_blocks = (NN * 64 + 255) / 256;  // one wave per node
  int gemm_blocks = NN / 16;                  // 50000 % 16 == 0

  // ---- layer 1 ----
  gather_mean<<<gather_blocks, 256, 0, stream>>>(x, row_start, srcs, agg);
  fused_layer<D, 128, true><<<gemm_blocks, 128, 0, stream>>>(
      agg, x, W1l, b1, W1r, g1, be1, m1, v1, h1, D);

  // ---- layer 2 (output in-place over h1) ----
  gather_mean<<<gather_blocks, 256, 0, stream>>>(h1, row_start, srcs, agg);
  fused_layer<D, 128, true><<<gemm_blocks, 128, 0, stream>>>(
      agg, h1, W2l, b2, W2r, g2, be2, m2, v2, h1, D);

  // ---- layer 3 (no BN/ReLU) ----
  gather_mean<<<gather_blocks, 256, 0, stream>>>(h1, row_start, srcs, agg);
  fused_layer<DOUT3, 64, false><<<gemm_blocks, 64, 0, stream>>>(
      agg, h1, W3l, b3, W3r, nullptr, nullptr, nullptr, nullptr, out, DOUT3);
}

// Round 4
// 294.370 us; speedup vs baseline: 11.1978x; 1.7018x over previous
//
#include <hip/hip_runtime.h>

#define NN 50000
#define NE 600000
#define D 128
#define DOUT3 47
#define BN_EPS 1e-5f
#define NPB 256

typedef __attribute__((ext_vector_type(8))) short short8;
typedef __attribute__((ext_vector_type(4))) float f32x4;

__device__ inline unsigned short f2b(float f) {
  union { float f; unsigned u; } c; c.f = f;
  unsigned u = c.u;
  unsigned r = (u + 0x7FFFu + ((u >> 16) & 1u)) >> 16;
  return (unsigned short)r;
}
__device__ inline float b2f(unsigned short h) {
  union { unsigned u; float f; } c; c.u = ((unsigned)h) << 16;
  return c.f;
}

// ---------------- CSR build ----------------
__global__ void zero_int(int* __restrict__ p, int n) {
  int i = blockIdx.x * blockDim.x + threadIdx.x;
  if (i < n) p[i] = 0;
}

__global__ void hist_kernel(const int* __restrict__ dst, int* __restrict__ deg, int E) {
  int e = blockIdx.x * blockDim.x + threadIdx.x;
  if (e < E) {
    int d = dst[e];
    d = max(0, min(NN - 1, d));
    atomicAdd(&deg[d], 1);
  }
}

__global__ __launch_bounds__(NPB) void scan_local(const int* __restrict__ deg,
                                                  int* __restrict__ row_start,
                                                  int* __restrict__ partials) {
  __shared__ int s[NPB];
  int t = threadIdx.x;
  int i = blockIdx.x * NPB + t;
  int v = (i < NN) ? deg[i] : 0;
  s[t] = v;
  __syncthreads();
  for (int off = 1; off < NPB; off <<= 1) {
    int u = (t >= off) ? s[t - off] : 0;
    __syncthreads();
    s[t] += u;
    __syncthreads();
  }
  if (i < NN) row_start[i] = s[t] - v;
  if (t == NPB - 1) partials[blockIdx.x] = s[NPB - 1];
}

__global__ __launch_bounds__(256) void scan_partials(int* __restrict__ partials, int nb) {
  __shared__ int s[256];
  int t = threadIdx.x;
  int v = (t < nb) ? partials[t] : 0;
  s[t] = v;
  __syncthreads();
  for (int off = 1; off < 256; off <<= 1) {
    int u = (t >= off) ? s[t - off] : 0;
    __syncthreads();
    s[t] += u;
    __syncthreads();
  }
  if (t < nb) partials[t] = s[t] - v;
}

__global__ __launch_bounds__(NPB) void scan_add(int* __restrict__ row_start,
                                                const int* __restrict__ partials,
                                                int* __restrict__ cursor) {
  int i = blockIdx.x * NPB + threadIdx.x;
  if (i < NN) {
    int r = row_start[i] + partials[blockIdx.x];
    row_start[i] = r;
    cursor[i] = r;
  }
  if (i == 0) row_start[NN] = NE;
}

__global__ void build_kernel(const int* __restrict__ src, const int* __restrict__ dst,
                             int* __restrict__ cursor, int* __restrict__ srcs, int E) {
  int e = blockIdx.x * blockDim.x + threadIdx.x;
  if (e < E) {
    int d = dst[e];
    d = max(0, min(NN - 1, d));
    int s = src[e];
    s = max(0, min(NN - 1, s));
    int pos = atomicAdd(&cursor[d], 1);
    srcs[pos] = s;
  }
}

// ---------------- conversions ----------------
__global__ void conv_bf16(const float4* __restrict__ in, unsigned short* __restrict__ outp,
                          long n4) {
  long i = (long)blockIdx.x * blockDim.x + threadIdx.x;
  long stride = (long)gridDim.x * blockDim.x;
  for (; i < n4; i += stride) {
    float4 v = in[i];
    uint2 p;
    p.x = (unsigned)f2b(v.x) | ((unsigned)f2b(v.y) << 16);
    p.y = (unsigned)f2b(v.z) | ((unsigned)f2b(v.w) << 16);
    *(uint2*)(outp + i * 4) = p;
  }
}

// Bt[j][k] (jpad x 256), k<128 -> Wl[k][j], k>=128 -> Wr[k-128][j]; zero-pad j>=dout.
__global__ void conv_w(const float* __restrict__ Wl, const float* __restrict__ Wr,
                       unsigned short* __restrict__ Bt, int dout, int jpad) {
  int idx = blockIdx.x * blockDim.x + threadIdx.x;
  int j = idx >> 8, k = idx & 255;
  if (j >= jpad) return;
  float v = 0.f;
  if (j < dout) v = (k < 128) ? Wl[k * dout + j] : Wr[(k - 128) * dout + j];
  Bt[idx] = f2b(v);
}

// ---------------- gather (bf16 in/out, fp32 accumulate) ----------------
__global__ __launch_bounds__(256) void gather_mean_b(const unsigned short* __restrict__ feat,
                                                     const int* __restrict__ row_start,
                                                     const int* __restrict__ srcs,
                                                     unsigned short* __restrict__ agg) {
  int node = (blockIdx.x * blockDim.x + threadIdx.x) >> 6;
  int lane = threadIdx.x & 63;
  if (node >= NN) return;
  int start = row_start[node], end = row_start[node + 1];
  float ax = 0.f, ay = 0.f;
  int j = start;
  for (; j + 1 < end; j += 2) {
    int s0 = srcs[j], s1 = srcs[j + 1];
    unsigned v0 = *(const unsigned*)(feat + (long)s0 * D + lane * 2);
    unsigned v1 = *(const unsigned*)(feat + (long)s1 * D + lane * 2);
    ax += b2f((unsigned short)v0) + b2f((unsigned short)v1);
    ay += b2f((unsigned short)(v0 >> 16)) + b2f((unsigned short)(v1 >> 16));
  }
  if (j < end) {
    unsigned v0 = *(const unsigned*)(feat + (long)srcs[j] * D + lane * 2);
    ax += b2f((unsigned short)v0);
    ay += b2f((unsigned short)(v0 >> 16));
  }
  float iv = 1.0f / fmaxf((float)(end - start), 1.0f);
  unsigned p = (unsigned)f2b(ax * iv) | ((unsigned)f2b(ay * iv) << 16);
  *(unsigned*)(agg + (long)node * D + lane * 2) = p;
}

// ---------------- fused MFMA layer ----------------
// One 64-lane wave per 16-row tile. C[16 x NF*16] = [agg | xin] (16x256) @ Bt^T.
// A-frag: lane holds A[lane&15][(lane>>4)*8 + 0..7]; B from Bt[col][k] same k-map.
// C/D: col = lane&15, row = (lane>>4)*4 + r.
template <int NF, bool BN, bool OUTF32>
__global__ __launch_bounds__(64) void fused_mfma(
    const unsigned short* __restrict__ aggb, const unsigned short* __restrict__ xb,
    const unsigned short* __restrict__ Bt, const float* __restrict__ bias,
    const float* __restrict__ g, const float* __restrict__ be,
    const float* __restrict__ m, const float* __restrict__ v,
    unsigned short* __restrict__ outb, float* __restrict__ outf, int dout) {
  int lane = threadIdx.x;
  int row0 = blockIdx.x * 16;
  int r15 = lane & 15, hi = lane >> 4;

  f32x4 acc[NF];
#pragma unroll
  for (int f = 0; f < NF; f++) acc[f] = (f32x4)(0.f);

  const unsigned short* Arow_a = aggb + (long)(row0 + r15) * D + hi * 8;
  const unsigned short* Arow_x = xb + (long)(row0 + r15) * D + hi * 8;
  const unsigned short* Bp = Bt + (long)r15 * 256 + hi * 8;

#pragma unroll
  for (int kf = 0; kf < 8; kf++) {
    const int kk = kf * 32;
    short8 a = *(const short8*)((kf < 4 ? Arow_a : Arow_x) + (kk & 127));
#pragma unroll
    for (int f = 0; f < NF; f++) {
      short8 b = *(const short8*)(Bp + (long)f * 16 * 256 + kk);
      acc[f] = __builtin_amdgcn_mfma_f32_16x16x32_bf16(a, b, acc[f], 0, 0, 0);
    }
  }

#pragma unroll
  for (int f = 0; f < NF; f++) {
    int col = f * 16 + r15;
    bool cok = col < dout;
    int cc = cok ? col : 0;
    float bj = bias[cc];
    float sc = 1.f, sh = 0.f;
    if (BN) {
      sc = g[cc] * rsqrtf(v[cc] + BN_EPS);
      sh = be[cc] - m[cc] * sc;
    }
#pragma unroll
    for (int r = 0; r < 4; r++) {
      int row = row0 + hi * 4 + r;
      float val = acc[f][r] + bj;
      if (BN) val = fmaxf(val * sc + sh, 0.f);
      if (cok) {
        if (OUTF32) outf[(long)row * dout + col] = val;
        else outb[(long)row * D + col] = f2b(val);
      }
    }
  }
}

extern "C" void kernel_launch(void* const* d_in, const int* in_sizes, int n_in,
                              void* d_out, int out_size, void* d_ws, size_t ws_size,
                              hipStream_t stream) {
  const float* x = (const float*)d_in[0];
  const int* ei = (const int*)d_in[1];
  const int* src = ei;
  const int* dst = ei + NE;
  const float* W1l = (const float*)d_in[2];
  const float* b1  = (const float*)d_in[3];
  const float* W1r = (const float*)d_in[4];
  const float* W2l = (const float*)d_in[5];
  const float* b2  = (const float*)d_in[6];
  const float* W2r = (const float*)d_in[7];
  const float* W3l = (const float*)d_in[8];
  const float* b3  = (const float*)d_in[9];
  const float* W3r = (const float*)d_in[10];
  const float* g1  = (const float*)d_in[11];
  const float* be1 = (const float*)d_in[12];
  const float* m1  = (const float*)d_in[13];
  const float* v1  = (const float*)d_in[14];
  const float* g2  = (const float*)d_in[15];
  const float* be2 = (const float*)d_in[16];
  const float* m2  = (const float*)d_in[17];
  const float* v2  = (const float*)d_in[18];

  float* out = (float*)d_out;

  const int SB = (NN + NPB - 1) / NPB;  // 196

  // ---- workspace layout (16B-aligned sections) ----
  int* deg       = (int*)d_ws;                 // 50000
  int* row_start = deg + NN;                   // 50004 (padded)
  int* cursor    = row_start + NN + 4;         // 50000
  int* partials  = cursor + NN;                // 256
  int* srcs      = partials + 256;             // 600000
  unsigned short* xb   = (unsigned short*)(srcs + NE);   // NN*D bf16
  unsigned short* aggb = xb + (long)NN * D;              // NN*D
  unsigned short* h1b  = aggb + (long)NN * D;            // NN*D
  unsigned short* Bt1  = h1b + (long)NN * D;             // 128*256
  unsigned short* Bt2  = Bt1 + 128 * 256;                // 128*256
  unsigned short* Bt3  = Bt2 + 128 * 256;                // 48*256

  // ---- CSR build ----
  zero_int<<<(NN + 255) / 256, 256, 0, stream>>>(deg, NN);
  hist_kernel<<<(NE + 255) / 256, 256, 0, stream>>>(dst, deg, NE);
  scan_local<<<SB, NPB, 0, stream>>>(deg, row_start, partials);
  scan_partials<<<1, 256, 0, stream>>>(partials, SB);
  scan_add<<<SB, NPB, 0, stream>>>(row_start, partials, cursor);
  build_kernel<<<(NE + 255) / 256, 256, 0, stream>>>(src, dst, cursor, srcs, NE);

  // ---- conversions ----
  conv_bf16<<<2048, 256, 0, stream>>>((const float4*)x, xb, (long)NN * D / 4);
  conv_w<<<(128 * 256) / 256, 256, 0, stream>>>(W1l, W1r, Bt1, D, 128);
  conv_w<<<(128 * 256) / 256, 256, 0, stream>>>(W2l, W2r, Bt2, D, 128);
  conv_w<<<(48 * 256) / 256, 256, 0, stream>>>(W3l, W3r, Bt3, DOUT3, 48);

  int gather_blocks = (NN * 64 + 255) / 256;
  int tiles = NN / 16;  // 3125

  // ---- layer 1 ----
  gather_mean_b<<<gather_blocks, 256, 0, stream>>>(xb, row_start, srcs, aggb);
  fused_mfma<8, true, false><<<tiles, 64, 0, stream>>>(
      aggb, xb, Bt1, b1, g1, be1, m1, v1, h1b, nullptr, D);

  // ---- layer 2 (in-place over h1b) ----
  gather_mean_b<<<gather_blocks, 256, 0, stream>>>(h1b, row_start, srcs, aggb);
  fused_mfma<8, true, false><<<tiles, 64, 0, stream>>>(
      aggb, h1b, Bt2, b2, g2, be2, m2, v2, h1b, nullptr, D);

  // ---- layer 3 (fp32 out, no BN) ----
  gather_mean_b<<<gather_blocks, 256, 0, stream>>>(h1b, row_start, srcs, aggb);
  fused_mfma<3, false, true><<<tiles, 64, 0, stream>>>(
      aggb, h1b, Bt3, b3, nullptr, nullptr, nullptr, nullptr, nullptr, out, DOUT3);
}

// Round 5
// 277.511 us; speedup vs baseline: 11.8781x; 1.0607x over previous
//
#include <hip/hip_runtime.h>

#define NN 50000
#define NE 600000
#define D 128
#define DOUT3 47
#define ZW 64   // padded Z width (bf16) for layer-3 gather
#define BN_EPS 1e-5f
#define NPB 256

typedef __attribute__((ext_vector_type(8))) short short8;
typedef __attribute__((ext_vector_type(4))) float f32x4;

__device__ inline unsigned short f2b(float f) {
  union { float f; unsigned u; } c; c.f = f;
  unsigned u = c.u;
  unsigned r = (u + 0x7FFFu + ((u >> 16) & 1u)) >> 16;
  return (unsigned short)r;
}
__device__ inline float b2f(unsigned short h) {
  union { unsigned u; float f; } c; c.u = ((unsigned)h) << 16;
  return c.f;
}

// ---------------- CSR build ----------------
__global__ void zero_int(int* __restrict__ p, int n) {
  int i = blockIdx.x * blockDim.x + threadIdx.x;
  if (i < n) p[i] = 0;
}

__global__ void hist_kernel(const int* __restrict__ dst, int* __restrict__ deg, int E) {
  int e = blockIdx.x * blockDim.x + threadIdx.x;
  if (e < E) {
    int d = dst[e];
    d = max(0, min(NN - 1, d));
    atomicAdd(&deg[d], 1);
  }
}

__global__ __launch_bounds__(NPB) void scan_local(const int* __restrict__ deg,
                                                  int* __restrict__ row_start,
                                                  int* __restrict__ partials) {
  __shared__ int s[NPB];
  int t = threadIdx.x;
  int i = blockIdx.x * NPB + t;
  int v = (i < NN) ? deg[i] : 0;
  s[t] = v;
  __syncthreads();
  for (int off = 1; off < NPB; off <<= 1) {
    int u = (t >= off) ? s[t - off] : 0;
    __syncthreads();
    s[t] += u;
    __syncthreads();
  }
  if (i < NN) row_start[i] = s[t] - v;
  if (t == NPB - 1) partials[blockIdx.x] = s[NPB - 1];
}

__global__ __launch_bounds__(256) void scan_partials(int* __restrict__ partials, int nb) {
  __shared__ int s[256];
  int t = threadIdx.x;
  int v = (t < nb) ? partials[t] : 0;
  s[t] = v;
  __syncthreads();
  for (int off = 1; off < 256; off <<= 1) {
    int u = (t >= off) ? s[t - off] : 0;
    __syncthreads();
    s[t] += u;
    __syncthreads();
  }
  if (t < nb) partials[t] = s[t] - v;
}

__global__ __launch_bounds__(NPB) void scan_add(int* __restrict__ row_start,
                                                const int* __restrict__ partials,
                                                int* __restrict__ cursor) {
  int i = blockIdx.x * NPB + threadIdx.x;
  if (i < NN) {
    int r = row_start[i] + partials[blockIdx.x];
    row_start[i] = r;
    cursor[i] = r;
  }
  if (i == 0) row_start[NN] = NE;
}

__global__ void build_kernel(const int* __restrict__ src, const int* __restrict__ dst,
                             int* __restrict__ cursor, int* __restrict__ srcs, int E) {
  int e = blockIdx.x * blockDim.x + threadIdx.x;
  if (e < E) {
    int d = dst[e];
    d = max(0, min(NN - 1, d));
    int s = src[e];
    s = max(0, min(NN - 1, s));
    int pos = atomicAdd(&cursor[d], 1);
    srcs[pos] = s;
  }
}

// ---------------- conversions ----------------
__global__ void conv_bf16(const float4* __restrict__ in, unsigned short* __restrict__ outp,
                          long n4) {
  long i = (long)blockIdx.x * blockDim.x + threadIdx.x;
  long stride = (long)gridDim.x * blockDim.x;
  for (; i < n4; i += stride) {
    float4 v = in[i];
    uint2 p;
    p.x = (unsigned)f2b(v.x) | ((unsigned)f2b(v.y) << 16);
    p.y = (unsigned)f2b(v.z) | ((unsigned)f2b(v.w) << 16);
    *(uint2*)(outp + i * 4) = p;
  }
}

// Bt[j][k] (jpad x 256), k<128 -> Wl[k][j], k>=128 -> Wr[k-128][j]; zero-pad j>=dout.
__global__ void conv_w(const float* __restrict__ Wl, const float* __restrict__ Wr,
                       unsigned short* __restrict__ Bt, int dout, int jpad) {
  int idx = blockIdx.x * blockDim.x + threadIdx.x;
  int j = idx >> 8, k = idx & 255;
  if (j >= jpad) return;
  float v = 0.f;
  if (j < dout) v = (k < 128) ? Wl[k * dout + j] : Wr[(k - 128) * dout + j];
  Bt[idx] = f2b(v);
}

// Bt3[j][k] (112 x 128): j<47 -> W3l[k][j]; 64<=j<111 -> W3r[k][j-64]; else 0.
__global__ void conv_w3(const float* __restrict__ W3l, const float* __restrict__ W3r,
                        unsigned short* __restrict__ Bt3) {
  int idx = blockIdx.x * blockDim.x + threadIdx.x;
  if (idx >= 112 * 128) return;
  int j = idx >> 7, k = idx & 127;
  float v = 0.f;
  if (j < DOUT3) v = W3l[k * DOUT3 + j];
  else if (j >= 64 && j < 64 + DOUT3) v = W3r[k * DOUT3 + (j - 64)];
  Bt3[idx] = f2b(v);
}

// ------------- edge-parallel gather: 4 x 16-lane groups, short8/lane -------------
__global__ __launch_bounds__(256) void gather_mean_b4(const unsigned short* __restrict__ feat,
                                                      const int* __restrict__ row_start,
                                                      const int* __restrict__ srcs,
                                                      unsigned short* __restrict__ agg) {
  int node = (blockIdx.x * blockDim.x + threadIdx.x) >> 6;
  int lane = threadIdx.x & 63;
  if (node >= NN) return;
  int g = lane >> 4, s = lane & 15;
  int start = row_start[node], end = row_start[node + 1];
  float a[8];
#pragma unroll
  for (int i = 0; i < 8; i++) a[i] = 0.f;
  for (int j = start + g; j < end; j += 4) {
    int sp = srcs[j];
    short8 v = *(const short8*)(feat + (long)sp * D + s * 8);
#pragma unroll
    for (int i = 0; i < 8; i++) a[i] += b2f((unsigned short)v[i]);
  }
#pragma unroll
  for (int i = 0; i < 8; i++) {
    a[i] += __shfl_xor(a[i], 16);
    a[i] += __shfl_xor(a[i], 32);
  }
  if (g == 0) {
    float iv = 1.0f / fmaxf((float)(end - start), 1.0f);
    uint4 p;
    p.x = (unsigned)f2b(a[0] * iv) | ((unsigned)f2b(a[1] * iv) << 16);
    p.y = (unsigned)f2b(a[2] * iv) | ((unsigned)f2b(a[3] * iv) << 16);
    p.z = (unsigned)f2b(a[4] * iv) | ((unsigned)f2b(a[5] * iv) << 16);
    p.w = (unsigned)f2b(a[6] * iv) | ((unsigned)f2b(a[7] * iv) << 16);
    *(uint4*)(agg + (long)node * D + s * 8) = p;
  }
}

// ------------- layer-3 gather: 47-wide Z rows (ZW=64 padded), add into P -------------
__global__ __launch_bounds__(256) void gather_add47(const unsigned short* __restrict__ Z,
                                                    const int* __restrict__ row_start,
                                                    const int* __restrict__ srcs,
                                                    float* __restrict__ outP) {
  int node = (blockIdx.x * blockDim.x + threadIdx.x) >> 6;
  int lane = threadIdx.x & 63;
  if (node >= NN) return;
  int g = lane >> 4, s = lane & 15;
  int start = row_start[node], end = row_start[node + 1];
  float a[4];
#pragma unroll
  for (int i = 0; i < 4; i++) a[i] = 0.f;
  for (int j = start + g; j < end; j += 4) {
    int sp = srcs[j];
    uint2 u = *(const uint2*)(Z + (long)sp * ZW + s * 4);
    a[0] += b2f((unsigned short)u.x);
    a[1] += b2f((unsigned short)(u.x >> 16));
    a[2] += b2f((unsigned short)u.y);
    a[3] += b2f((unsigned short)(u.y >> 16));
  }
#pragma unroll
  for (int i = 0; i < 4; i++) {
    a[i] += __shfl_xor(a[i], 16);
    a[i] += __shfl_xor(a[i], 32);
  }
  if (g == 0) {
    float iv = 1.0f / fmaxf((float)(end - start), 1.0f);
#pragma unroll
    for (int i = 0; i < 4; i++) {
      int c = s * 4 + i;
      if (c < DOUT3) {
        long o = (long)node * DOUT3 + c;
        outP[o] = outP[o] + a[i] * iv;
      }
    }
  }
}

// ---------------- fused MFMA layer (layers 1-2), 4 waves/block ----------------
// C[16 x 128] = [agg | xin] (16x256) @ Bt^T ; BN+ReLU epilogue; bf16 out.
__global__ __launch_bounds__(256) void fused_mfma(
    const unsigned short* __restrict__ aggb, const unsigned short* __restrict__ xb,
    const unsigned short* __restrict__ Bt, const float* __restrict__ bias,
    const float* __restrict__ g, const float* __restrict__ be,
    const float* __restrict__ m, const float* __restrict__ v,
    unsigned short* __restrict__ outb, int tiles) {
  const int NF = 8;
  int wid = threadIdx.x >> 6, lane = threadIdx.x & 63;
  int tile = blockIdx.x * 4 + wid;
  if (tile >= tiles) return;
  int row0 = tile * 16;
  int r15 = lane & 15, hi = lane >> 4;

  f32x4 acc[NF];
#pragma unroll
  for (int f = 0; f < NF; f++) acc[f] = (f32x4)(0.f);

  const unsigned short* Arow_a = aggb + (long)(row0 + r15) * D + hi * 8;
  const unsigned short* Arow_x = xb + (long)(row0 + r15) * D + hi * 8;
  const unsigned short* Bp = Bt + (long)r15 * 256 + hi * 8;

#pragma unroll
  for (int kf = 0; kf < 8; kf++) {
    const int kk = kf * 32;
    short8 a = *(const short8*)((kf < 4 ? Arow_a : Arow_x) + (kk & 127));
#pragma unroll
    for (int f = 0; f < NF; f++) {
      short8 b = *(const short8*)(Bp + (long)f * 16 * 256 + kk);
      acc[f] = __builtin_amdgcn_mfma_f32_16x16x32_bf16(a, b, acc[f], 0, 0, 0);
    }
  }

#pragma unroll
  for (int f = 0; f < NF; f++) {
    int col = f * 16 + r15;
    float bj = bias[col];
    float sc = g[col] * rsqrtf(v[col] + BN_EPS);
    float sh = be[col] - m[col] * sc;
#pragma unroll
    for (int r = 0; r < 4; r++) {
      int row = row0 + hi * 4 + r;
      float val = fmaxf((acc[f][r] + bj) * sc + sh, 0.f);
      outb[(long)row * D + col] = f2b(val);
    }
  }
}

// ---------------- layer-3 transform: [Z | P] = h @ [W3l | W3r], 4 waves/block --------
// NF=7 frags (112 cols): cols 0..63 -> Z (48 real + 16 zero-pad), cols 64..110 -> P+bias.
__global__ __launch_bounds__(256) void trans_mfma(
    const unsigned short* __restrict__ xb, const unsigned short* __restrict__ Bt3,
    const float* __restrict__ bias, unsigned short* __restrict__ Z,
    float* __restrict__ outP, int tiles) {
  const int NF = 7;
  int wid = threadIdx.x >> 6, lane = threadIdx.x & 63;
  int tile = blockIdx.x * 4 + wid;
  if (tile >= tiles) return;
  int row0 = tile * 16;
  int r15 = lane & 15, hi = lane >> 4;

  f32x4 acc[NF];
#pragma unroll
  for (int f = 0; f < NF; f++) acc[f] = (f32x4)(0.f);

  const unsigned short* Ar = xb + (long)(row0 + r15) * D + hi * 8;
  const unsigned short* Bp = Bt3 + (long)r15 * 128 + hi * 8;

#pragma unroll
  for (int kf = 0; kf < 4; kf++) {
    const int kk = kf * 32;
    short8 a = *(const short8*)(Ar + kk);
#pragma unroll
    for (int f = 0; f < NF; f++) {
      short8 b = *(const short8*)(Bp + (long)f * 16 * 128 + kk);
      acc[f] = __builtin_amdgcn_mfma_f32_16x16x32_bf16(a, b, acc[f], 0, 0, 0);
    }
  }

#pragma unroll
  for (int f = 0; f < NF; f++) {
    int col = f * 16 + r15;
#pragma unroll
    for (int r = 0; r < 4; r++) {
      int row = row0 + hi * 4 + r;
      float val = acc[f][r];
      if (col < ZW) {
        Z[(long)row * ZW + col] = f2b(val);  // cols 48..63 are exact zeros (zero B rows)
      } else {
        int pc = col - 64;
        if (pc < DOUT3) outP[(long)row * DOUT3 + pc] = val + bias[pc];
      }
    }
  }
}

extern "C" void kernel_launch(void* const* d_in, const int* in_sizes, int n_in,
                              void* d_out, int out_size, void* d_ws, size_t ws_size,
                              hipStream_t stream) {
  const float* x = (const float*)d_in[0];
  const int* ei = (const int*)d_in[1];
  const int* src = ei;
  const int* dst = ei + NE;
  const float* W1l = (const float*)d_in[2];
  const float* b1  = (const float*)d_in[3];
  const float* W1r = (const float*)d_in[4];
  const float* W2l = (const float*)d_in[5];
  const float* b2  = (const float*)d_in[6];
  const float* W2r = (const float*)d_in[7];
  const float* W3l = (const float*)d_in[8];
  const float* b3  = (const float*)d_in[9];
  const float* W3r = (const float*)d_in[10];
  const float* g1  = (const float*)d_in[11];
  const float* be1 = (const float*)d_in[12];
  const float* m1  = (const float*)d_in[13];
  const float* v1  = (const float*)d_in[14];
  const float* g2  = (const float*)d_in[15];
  const float* be2 = (const float*)d_in[16];
  const float* m2  = (const float*)d_in[17];
  const float* v2  = (const float*)d_in[18];

  float* out = (float*)d_out;

  const int SB = (NN + NPB - 1) / NPB;  // 196

  // ---- workspace layout ----
  int* deg       = (int*)d_ws;                 // NN
  int* row_start = deg + NN;                   // NN+4
  int* cursor    = row_start + NN + 4;         // NN
  int* partials  = cursor + NN;                // 256
  int* srcs      = partials + 256;             // NE
  unsigned short* xb   = (unsigned short*)(srcs + NE);   // NN*D
  unsigned short* aggb = xb + (long)NN * D;              // NN*D
  unsigned short* h1b  = aggb + (long)NN * D;            // NN*D
  unsigned short* Zb   = h1b + (long)NN * D;             // NN*ZW
  unsigned short* Bt1  = Zb + (long)NN * ZW;             // 128*256
  unsigned short* Bt2  = Bt1 + 128 * 256;                // 128*256
  unsigned short* Bt3  = Bt2 + 128 * 256;                // 112*128

  // ---- CSR build ----
  zero_int<<<(NN + 255) / 256, 256, 0, stream>>>(deg, NN);
  hist_kernel<<<(NE + 255) / 256, 256, 0, stream>>>(dst, deg, NE);
  scan_local<<<SB, NPB, 0, stream>>>(deg, row_start, partials);
  scan_partials<<<1, 256, 0, stream>>>(partials, SB);
  scan_add<<<SB, NPB, 0, stream>>>(row_start, partials, cursor);
  build_kernel<<<(NE + 255) / 256, 256, 0, stream>>>(src, dst, cursor, srcs, NE);

  // ---- conversions ----
  conv_bf16<<<2048, 256, 0, stream>>>((const float4*)x, xb, (long)NN * D / 4);
  conv_w<<<(128 * 256) / 256, 256, 0, stream>>>(W1l, W1r, Bt1, D, 128);
  conv_w<<<(128 * 256) / 256, 256, 0, stream>>>(W2l, W2r, Bt2, D, 128);
  conv_w3<<<(112 * 128 + 255) / 256, 256, 0, stream>>>(W3l, W3r, Bt3);

  int gather_blocks = (NN * 64 + 255) / 256;  // one wave per node
  int tiles = NN / 16;                        // 3125
  int mfma_blocks = (tiles + 3) / 4;

  // ---- layer 1 ----
  gather_mean_b4<<<gather_blocks, 256, 0, stream>>>(xb, row_start, srcs, aggb);
  fused_mfma<<<mfma_blocks, 256, 0, stream>>>(
      aggb, xb, Bt1, b1, g1, be1, m1, v1, h1b, tiles);

  // ---- layer 2 (in-place over h1b) ----
  gather_mean_b4<<<gather_blocks, 256, 0, stream>>>(h1b, row_start, srcs, aggb);
  fused_mfma<<<mfma_blocks, 256, 0, stream>>>(
      aggb, h1b, Bt2, b2, g2, be2, m2, v2, h1b, tiles);

  // ---- layer 3: transform then 47-wide gather-add ----
  trans_mfma<<<mfma_blocks, 256, 0, stream>>>(h1b, Bt3, b3, Zb, out, tiles);
  gather_add47<<<gather_blocks, 256, 0, stream>>>(Zb, row_start, srcs, out);
}

// Round 7
// 253.653 us; speedup vs baseline: 12.9953x; 1.0941x over previous
//
#include <hip/hip_runtime.h>

#define NN 50000
#define NE 600000
#define D 128
#define DOUT3 47
#define ZW 64   // padded Z width (bf16) for layer-3 gather
#define BN_EPS 1e-5f
#define NPB 256
#define SB 196  // scan blocks = ceil(NN/NPB)

typedef __attribute__((ext_vector_type(8))) short short8;
typedef __attribute__((ext_vector_type(4))) float f32x4;

__device__ inline unsigned short f2b(float f) {
  union { float f; unsigned u; } c; c.f = f;
  unsigned u = c.u;
  unsigned r = (u + 0x7FFFu + ((u >> 16) & 1u)) >> 16;
  return (unsigned short)r;
}
__device__ inline float b2f(unsigned short h) {
  union { unsigned u; float f; } c; c.u = ((unsigned)h) << 16;
  return c.f;
}

// ---------------- merged prep: conv_bf16 | zero deg | conv Bt1 | Bt2 | Bt3 ----------
// block ranges: [0,1024) conv_bf16 grid-stride; [1024,1220) zero deg;
// [1220,1348) Bt1; [1348,1476) Bt2; [1476,1532) Bt3.
__global__ __launch_bounds__(256) void prep_kernel(
    const float4* __restrict__ x4, unsigned short* __restrict__ xb,
    int* __restrict__ deg,
    const float* __restrict__ W1l, const float* __restrict__ W1r, unsigned short* __restrict__ Bt1,
    const float* __restrict__ W2l, const float* __restrict__ W2r, unsigned short* __restrict__ Bt2,
    const float* __restrict__ W3l, const float* __restrict__ W3r, unsigned short* __restrict__ Bt3) {
  int b = blockIdx.x;
  int t = threadIdx.x;
  if (b < 1024) {
    long n4 = (long)NN * D / 4;
    for (long i = (long)b * 256 + t; i < n4; i += 1024L * 256) {
      float4 v = x4[i];
      uint2 p;
      p.x = (unsigned)f2b(v.x) | ((unsigned)f2b(v.y) << 16);
      p.y = (unsigned)f2b(v.z) | ((unsigned)f2b(v.w) << 16);
      *(uint2*)(xb + i * 4) = p;
    }
  } else if (b < 1220) {
    int i = (b - 1024) * 256 + t;
    if (i < NN) deg[i] = 0;
  } else if (b < 1476) {
    const float* Wl = (b < 1348) ? W1l : W2l;
    const float* Wr = (b < 1348) ? W1r : W2r;
    unsigned short* Bt = (b < 1348) ? Bt1 : Bt2;
    int idx = ((b < 1348) ? (b - 1220) : (b - 1348)) * 256 + t;
    int j = idx >> 8, k = idx & 255;
    float v = (k < 128) ? Wl[k * D + j] : Wr[(k - 128) * D + j];
    Bt[idx] = f2b(v);
  } else {
    int idx = (b - 1476) * 256 + t;
    if (idx < 112 * 128) {
      int j = idx >> 7, k = idx & 127;
      float v = 0.f;
      if (j < DOUT3) v = W3l[k * DOUT3 + j];
      else if (j >= 64 && j < 64 + DOUT3) v = W3r[k * DOUT3 + (j - 64)];
      Bt3[idx] = f2b(v);
    }
  }
}

// ---------------- CSR build ----------------
__global__ void hist_kernel(const int* __restrict__ dst, int* __restrict__ deg, int E) {
  int e = blockIdx.x * blockDim.x + threadIdx.x;
  if (e < E) {
    int d = dst[e];
    d = max(0, min(NN - 1, d));
    atomicAdd(&deg[d], 1);
  }
}

__global__ __launch_bounds__(NPB) void scan_local(const int* __restrict__ deg,
                                                  int* __restrict__ row_start,
                                                  int* __restrict__ partials) {
  __shared__ int s[NPB];
  int t = threadIdx.x;
  int i = blockIdx.x * NPB + t;
  int v = (i < NN) ? deg[i] : 0;
  s[t] = v;
  __syncthreads();
  for (int off = 1; off < NPB; off <<= 1) {
    int u = (t >= off) ? s[t - off] : 0;
    __syncthreads();
    s[t] += u;
    __syncthreads();
  }
  if (i < NN) row_start[i] = s[t] - v;
  if (t == NPB - 1) partials[blockIdx.x] = s[NPB - 1];
}

// scan of partials folded in: every block redundantly scans the 196 partials in LDS.
__global__ __launch_bounds__(NPB) void scan_add(int* __restrict__ row_start,
                                                const int* __restrict__ partials,
                                                int* __restrict__ cursor) {
  __shared__ int s[NPB];
  int t = threadIdx.x;
  int v = (t < SB) ? partials[t] : 0;
  s[t] = v;
  __syncthreads();
  for (int off = 1; off < NPB; off <<= 1) {
    int u = (t >= off) ? s[t - off] : 0;
    __syncthreads();
    s[t] += u;
    __syncthreads();
  }
  int base = s[blockIdx.x] - partials[blockIdx.x];  // exclusive prefix of this block
  int i = blockIdx.x * NPB + t;
  if (i < NN) {
    int r = row_start[i] + base;
    row_start[i] = r;
    cursor[i] = r;
  }
  if (i == 0) row_start[NN] = NE;
}

__global__ void build_kernel(const int* __restrict__ src, const int* __restrict__ dst,
                             int* __restrict__ cursor, int* __restrict__ srcs, int E) {
  int e = blockIdx.x * blockDim.x + threadIdx.x;
  if (e < E) {
    int d = dst[e];
    d = max(0, min(NN - 1, d));
    int s = src[e];
    s = max(0, min(NN - 1, s));
    int pos = atomicAdd(&cursor[d], 1);
    srcs[pos] = s;
  }
}

// ------------- gather: index-preload + branchless 2-deep row loads -------------
// 4 x 16-lane groups per wave. Uniform trip count M; __shfl always executed by
// ALL 64 lanes (cross-lane reads from exec-masked lanes return 0 on CDNA — the
// round-6 bug). Invalid edges contribute via weight 0 (they read row 0, cached).
__global__ __launch_bounds__(256) void gather_mean_b4(const unsigned short* __restrict__ feat,
                                                      const int* __restrict__ row_start,
                                                      const int* __restrict__ srcs,
                                                      unsigned short* __restrict__ agg) {
  int node = (blockIdx.x * blockDim.x + threadIdx.x) >> 6;
  int lane = threadIdx.x & 63;
  if (node >= NN) return;
  int g = lane >> 4, s = lane & 15;
  int start = row_start[node], end = row_start[node + 1];
  float a[8];
#pragma unroll
  for (int i = 0; i < 8; i++) a[i] = 0.f;
  const unsigned short* fp = feat + s * 8;
  for (int base = start; base < end; base += 64) {
    int cnt = min(end - base, 64);                 // wave-uniform
    int idxv = (base + lane < end) ? srcs[base + lane] : 0;
    int M = (cnt + 3) >> 2;                        // wave-uniform trip count
    for (int m = 0; m < M; m += 2) {
      int e0 = m * 4 + g;                          // <= 59
      int e1 = e0 + 4;                             // <= 63
      int s0 = __shfl(idxv, e0);                   // all lanes active here
      int s1 = __shfl(idxv, e1);
      float w0 = (e0 < cnt) ? 1.f : 0.f;
      float w1 = (e1 < cnt) ? 1.f : 0.f;
      short8 v0 = *(const short8*)(fp + (long)s0 * D);
      short8 v1 = *(const short8*)(fp + (long)s1 * D);
#pragma unroll
      for (int i = 0; i < 8; i++)
        a[i] += w0 * b2f((unsigned short)v0[i]) + w1 * b2f((unsigned short)v1[i]);
    }
  }
#pragma unroll
  for (int i = 0; i < 8; i++) {
    a[i] += __shfl_xor(a[i], 16);
    a[i] += __shfl_xor(a[i], 32);
  }
  if (g == 0) {
    float iv = 1.0f / fmaxf((float)(end - start), 1.0f);
    uint4 p;
    p.x = (unsigned)f2b(a[0] * iv) | ((unsigned)f2b(a[1] * iv) << 16);
    p.y = (unsigned)f2b(a[2] * iv) | ((unsigned)f2b(a[3] * iv) << 16);
    p.z = (unsigned)f2b(a[4] * iv) | ((unsigned)f2b(a[5] * iv) << 16);
    p.w = (unsigned)f2b(a[6] * iv) | ((unsigned)f2b(a[7] * iv) << 16);
    *(uint4*)(agg + (long)node * D + s * 8) = p;
  }
}

// ------------- layer-3 gather: 47-wide Z rows (ZW=64 padded), add into P -------------
__global__ __launch_bounds__(256) void gather_add47(const unsigned short* __restrict__ Z,
                                                    const int* __restrict__ row_start,
                                                    const int* __restrict__ srcs,
                                                    float* __restrict__ outP) {
  int node = (blockIdx.x * blockDim.x + threadIdx.x) >> 6;
  int lane = threadIdx.x & 63;
  if (node >= NN) return;
  int g = lane >> 4, s = lane & 15;
  int start = row_start[node], end = row_start[node + 1];
  float a[4];
#pragma unroll
  for (int i = 0; i < 4; i++) a[i] = 0.f;
  const unsigned short* zp = Z + s * 4;
  for (int base = start; base < end; base += 64) {
    int cnt = min(end - base, 64);
    int idxv = (base + lane < end) ? srcs[base + lane] : 0;
    int M = (cnt + 3) >> 2;
    for (int m = 0; m < M; m += 2) {
      int e0 = m * 4 + g;
      int e1 = e0 + 4;
      int s0 = __shfl(idxv, e0);
      int s1 = __shfl(idxv, e1);
      float w0 = (e0 < cnt) ? 1.f : 0.f;
      float w1 = (e1 < cnt) ? 1.f : 0.f;
      uint2 u0 = *(const uint2*)(zp + (long)s0 * ZW);
      uint2 u1 = *(const uint2*)(zp + (long)s1 * ZW);
      a[0] += w0 * b2f((unsigned short)u0.x) + w1 * b2f((unsigned short)u1.x);
      a[1] += w0 * b2f((unsigned short)(u0.x >> 16)) + w1 * b2f((unsigned short)(u1.x >> 16));
      a[2] += w0 * b2f((unsigned short)u0.y) + w1 * b2f((unsigned short)u1.y);
      a[3] += w0 * b2f((unsigned short)(u0.y >> 16)) + w1 * b2f((unsigned short)(u1.y >> 16));
    }
  }
#pragma unroll
  for (int i = 0; i < 4; i++) {
    a[i] += __shfl_xor(a[i], 16);
    a[i] += __shfl_xor(a[i], 32);
  }
  if (g == 0) {
    float iv = 1.0f / fmaxf((float)(end - start), 1.0f);
#pragma unroll
    for (int i = 0; i < 4; i++) {
      int c = s * 4 + i;
      if (c < DOUT3) {
        long o = (long)node * DOUT3 + c;
        outP[o] = outP[o] + a[i] * iv;
      }
    }
  }
}

// ---------------- fused MFMA layer (layers 1-2), 4 waves/block ----------------
__global__ __launch_bounds__(256) void fused_mfma(
    const unsigned short* __restrict__ aggb, const unsigned short* __restrict__ xb,
    const unsigned short* __restrict__ Bt, const float* __restrict__ bias,
    const float* __restrict__ g, const float* __restrict__ be,
    const float* __restrict__ m, const float* __restrict__ v,
    unsigned short* __restrict__ outb, int tiles) {
  const int NF = 8;
  int wid = threadIdx.x >> 6, lane = threadIdx.x & 63;
  int tile = blockIdx.x * 4 + wid;
  if (tile >= tiles) return;
  int row0 = tile * 16;
  int r15 = lane & 15, hi = lane >> 4;

  f32x4 acc[NF];
#pragma unroll
  for (int f = 0; f < NF; f++) acc[f] = (f32x4)(0.f);

  const unsigned short* Arow_a = aggb + (long)(row0 + r15) * D + hi * 8;
  const unsigned short* Arow_x = xb + (long)(row0 + r15) * D + hi * 8;
  const unsigned short* Bp = Bt + (long)r15 * 256 + hi * 8;

#pragma unroll
  for (int kf = 0; kf < 8; kf++) {
    const int kk = kf * 32;
    short8 a = *(const short8*)((kf < 4 ? Arow_a : Arow_x) + (kk & 127));
#pragma unroll
    for (int f = 0; f < NF; f++) {
      short8 b = *(const short8*)(Bp + (long)f * 16 * 256 + kk);
      acc[f] = __builtin_amdgcn_mfma_f32_16x16x32_bf16(a, b, acc[f], 0, 0, 0);
    }
  }

#pragma unroll
  for (int f = 0; f < NF; f++) {
    int col = f * 16 + r15;
    float bj = bias[col];
    float sc = g[col] * rsqrtf(v[col] + BN_EPS);
    float sh = be[col] - m[col] * sc;
#pragma unroll
    for (int r = 0; r < 4; r++) {
      int row = row0 + hi * 4 + r;
      float val = fmaxf((acc[f][r] + bj) * sc + sh, 0.f);
      outb[(long)row * D + col] = f2b(val);
    }
  }
}

// ---------------- layer-3 transform: [Z | P] = h @ [W3l | W3r] ----------------
__global__ __launch_bounds__(256) void trans_mfma(
    const unsigned short* __restrict__ xb, const unsigned short* __restrict__ Bt3,
    const float* __restrict__ bias, unsigned short* __restrict__ Z,
    float* __restrict__ outP, int tiles) {
  const int NF = 7;
  int wid = threadIdx.x >> 6, lane = threadIdx.x & 63;
  int tile = blockIdx.x * 4 + wid;
  if (tile >= tiles) return;
  int row0 = tile * 16;
  int r15 = lane & 15, hi = lane >> 4;

  f32x4 acc[NF];
#pragma unroll
  for (int f = 0; f < NF; f++) acc[f] = (f32x4)(0.f);

  const unsigned short* Ar = xb + (long)(row0 + r15) * D + hi * 8;
  const unsigned short* Bp = Bt3 + (long)r15 * 128 + hi * 8;

#pragma unroll
  for (int kf = 0; kf < 4; kf++) {
    const int kk = kf * 32;
    short8 a = *(const short8*)(Ar + kk);
#pragma unroll
    for (int f = 0; f < NF; f++) {
      short8 b = *(const short8*)(Bp + (long)f * 16 * 128 + kk);
      acc[f] = __builtin_amdgcn_mfma_f32_16x16x32_bf16(a, b, acc[f], 0, 0, 0);
    }
  }

#pragma unroll
  for (int f = 0; f < NF; f++) {
    int col = f * 16 + r15;
#pragma unroll
    for (int r = 0; r < 4; r++) {
      int row = row0 + hi * 4 + r;
      float val = acc[f][r];
      if (col < ZW) {
        Z[(long)row * ZW + col] = f2b(val);
      } else {
        int pc = col - 64;
        if (pc < DOUT3) outP[(long)row * DOUT3 + pc] = val + bias[pc];
      }
    }
  }
}

extern "C" void kernel_launch(void* const* d_in, const int* in_sizes, int n_in,
                              void* d_out, int out_size, void* d_ws, size_t ws_size,
                              hipStream_t stream) {
  const float* x = (const float*)d_in[0];
  const int* ei = (const int*)d_in[1];
  const int* src = ei;
  const int* dst = ei + NE;
  const float* W1l = (const float*)d_in[2];
  const float* b1  = (const float*)d_in[3];
  const float* W1r = (const float*)d_in[4];
  const float* W2l = (const float*)d_in[5];
  const float* b2  = (const float*)d_in[6];
  const float* W2r = (const float*)d_in[7];
  const float* W3l = (const float*)d_in[8];
  const float* b3  = (const float*)d_in[9];
  const float* W3r = (const float*)d_in[10];
  const float* g1  = (const float*)d_in[11];
  const float* be1 = (const float*)d_in[12];
  const float* m1  = (const float*)d_in[13];
  const float* v1  = (const float*)d_in[14];
  const float* g2  = (const float*)d_in[15];
  const float* be2 = (const float*)d_in[16];
  const float* m2  = (const float*)d_in[17];
  const float* v2  = (const float*)d_in[18];

  float* out = (float*)d_out;

  // ---- workspace layout ----
  int* deg       = (int*)d_ws;                 // NN
  int* row_start = deg + NN;                   // NN+4
  int* cursor    = row_start + NN + 4;         // NN
  int* partials  = cursor + NN;                // 256
  int* srcs      = partials + 256;             // NE
  unsigned short* xb   = (unsigned short*)(srcs + NE);   // NN*D
  unsigned short* aggb = xb + (long)NN * D;              // NN*D
  unsigned short* h1b  = aggb + (long)NN * D;            // NN*D
  unsigned short* Zb   = h1b + (long)NN * D;             // NN*ZW
  unsigned short* Bt1  = Zb + (long)NN * ZW;             // 128*256
  unsigned short* Bt2  = Bt1 + 128 * 256;                // 128*256
  unsigned short* Bt3  = Bt2 + 128 * 256;                // 112*128

  // ---- prep (conversions + zero deg, merged) ----
  prep_kernel<<<1532, 256, 0, stream>>>(
      (const float4*)x, xb, deg, W1l, W1r, Bt1, W2l, W2r, Bt2, W3l, W3r, Bt3);

  // ---- CSR build ----
  hist_kernel<<<(NE + 255) / 256, 256, 0, stream>>>(dst, deg, NE);
  scan_local<<<SB, NPB, 0, stream>>>(deg, row_start, partials);
  scan_add<<<SB, NPB, 0, stream>>>(row_start, partials, cursor);
  build_kernel<<<(NE + 255) / 256, 256, 0, stream>>>(src, dst, cursor, srcs, NE);

  int gather_blocks = (NN * 64 + 255) / 256;  // one wave per node
  int tiles = NN / 16;                        // 3125
  int mfma_blocks = (tiles + 3) / 4;

  // ---- layer 1 ----
  gather_mean_b4<<<gather_blocks, 256, 0, stream>>>(xb, row_start, srcs, aggb);
  fused_mfma<<<mfma_blocks, 256, 0, stream>>>(
      aggb, xb, Bt1, b1, g1, be1, m1, v1, h1b, tiles);

  // ---- layer 2 (in-place over h1b) ----
  gather_mean_b4<<<gather_blocks, 256, 0, stream>>>(h1b, row_start, srcs, aggb);
  fused_mfma<<<mfma_blocks, 256, 0, stream>>>(
      aggb, h1b, Bt2, b2, g2, be2, m2, v2, h1b, tiles);

  // ---- layer 3: transform then 47-wide gather-add ----
  trans_mfma<<<mfma_blocks, 256, 0, stream>>>(h1b, Bt3, b3, Zb, out, tiles);
  gather_add47<<<gather_blocks, 256, 0, stream>>>(Zb, row_start, srcs, out);
}

// Round 9
// 237.130 us; speedup vs baseline: 13.9008x; 1.0697x over previous
//
#include <hip/hip_runtime.h>

#define NN 50000
#define NE 600000
#define D 128
#define DOUT3 47
#define ZW 64   // padded Z width (bf16) for layer-3 gather
#define BN_EPS 1e-5f
#define NPB 256
#define SB 196  // scan blocks = ceil(NN/NPB)

typedef __attribute__((ext_vector_type(8))) short short8;
typedef __attribute__((ext_vector_type(4))) float f32x4;

__device__ inline unsigned short f2b(float f) {
  union { float f; unsigned u; } c; c.f = f;
  unsigned u = c.u;
  unsigned r = (u + 0x7FFFu + ((u >> 16) & 1u)) >> 16;
  return (unsigned short)r;
}
__device__ inline float b2f(unsigned short h) {
  union { unsigned u; float f; } c; c.u = ((unsigned)h) << 16;
  return c.f;
}

// ---------------- zero deg (must precede prep_hist's atomics) ----------------
__global__ void zero_int(int* __restrict__ p, int n) {
  int i = blockIdx.x * blockDim.x + threadIdx.x;
  if (i < n) p[i] = 0;
}

// ------- merged prep+hist: conv_bf16 | Bt1 | Bt2 | Bt3 | hist atomics -------
// block ranges: [0,1024) conv x; [1024,1152) Bt1; [1152,1280) Bt2;
// [1280,1336) Bt3; [1336,3680) hist.
__global__ __launch_bounds__(256) void prep_hist(
    const float4* __restrict__ x4, unsigned short* __restrict__ xb,
    const float* __restrict__ W1l, const float* __restrict__ W1r, unsigned short* __restrict__ Bt1,
    const float* __restrict__ W2l, const float* __restrict__ W2r, unsigned short* __restrict__ Bt2,
    const float* __restrict__ W3l, const float* __restrict__ W3r, unsigned short* __restrict__ Bt3,
    const int* __restrict__ dst, int* __restrict__ deg) {
  int b = blockIdx.x;
  int t = threadIdx.x;
  if (b < 1024) {
    long n4 = (long)NN * D / 4;
    for (long i = (long)b * 256 + t; i < n4; i += 1024L * 256) {
      float4 v = x4[i];
      uint2 p;
      p.x = (unsigned)f2b(v.x) | ((unsigned)f2b(v.y) << 16);
      p.y = (unsigned)f2b(v.z) | ((unsigned)f2b(v.w) << 16);
      *(uint2*)(xb + i * 4) = p;
    }
  } else if (b < 1280) {
    const float* Wl = (b < 1152) ? W1l : W2l;
    const float* Wr = (b < 1152) ? W1r : W2r;
    unsigned short* Bt = (b < 1152) ? Bt1 : Bt2;
    int idx = ((b < 1152) ? (b - 1024) : (b - 1152)) * 256 + t;
    int j = idx >> 8, k = idx & 255;
    float v = (k < 128) ? Wl[k * D + j] : Wr[(k - 128) * D + j];
    Bt[idx] = f2b(v);
  } else if (b < 1336) {
    int idx = (b - 1280) * 256 + t;
    if (idx < 112 * 128) {
      int j = idx >> 7, k = idx & 127;
      float v = 0.f;
      if (j < DOUT3) v = W3l[k * DOUT3 + j];
      else if (j >= 64 && j < 64 + DOUT3) v = W3r[k * DOUT3 + (j - 64)];
      Bt3[idx] = f2b(v);
    }
  } else {
    int e = (b - 1336) * 256 + t;
    if (e < NE) {
      int d = dst[e];
      d = max(0, min(NN - 1, d));
      atomicAdd(&deg[d], 1);
    }
  }
}

// ---------------- CSR scan + build ----------------
__global__ __launch_bounds__(NPB) void scan_local(const int* __restrict__ deg,
                                                  int* __restrict__ row_start,
                                                  int* __restrict__ partials) {
  __shared__ int s[NPB];
  int t = threadIdx.x;
  int i = blockIdx.x * NPB + t;
  int v = (i < NN) ? deg[i] : 0;
  s[t] = v;
  __syncthreads();
  for (int off = 1; off < NPB; off <<= 1) {
    int u = (t >= off) ? s[t - off] : 0;
    __syncthreads();
    s[t] += u;
    __syncthreads();
  }
  if (i < NN) row_start[i] = s[t] - v;
  if (t == NPB - 1) partials[blockIdx.x] = s[NPB - 1];
}

__global__ __launch_bounds__(NPB) void scan_add(int* __restrict__ row_start,
                                                const int* __restrict__ partials,
                                                int* __restrict__ cursor) {
  __shared__ int s[NPB];
  int t = threadIdx.x;
  int v = (t < SB) ? partials[t] : 0;
  s[t] = v;
  __syncthreads();
  for (int off = 1; off < NPB; off <<= 1) {
    int u = (t >= off) ? s[t - off] : 0;
    __syncthreads();
    s[t] += u;
    __syncthreads();
  }
  int base = s[blockIdx.x] - partials[blockIdx.x];
  int i = blockIdx.x * NPB + t;
  if (i < NN) {
    int r = row_start[i] + base;
    row_start[i] = r;
    cursor[i] = r;
  }
  if (i == 0) row_start[NN] = NE;
}

__global__ void build_kernel(const int* __restrict__ src, const int* __restrict__ dst,
                             int* __restrict__ cursor, int* __restrict__ srcs, int E) {
  int e = blockIdx.x * blockDim.x + threadIdx.x;
  if (e < E) {
    int d = dst[e];
    d = max(0, min(NN - 1, d));
    int s = src[e];
    s = max(0, min(NN - 1, s));
    int pos = atomicAdd(&cursor[d], 1);
    srcs[pos] = s;
  }
}

// ---------------- fused gather + MFMA layer (layers 1-2) ----------------
// One wave per 16-row tile, 4 waves/block. Gather: each 16-lane group owns one
// node per round (4 rounds); lane s accumulates cols [8s,8s+8) (2-deep ILP).
// Index broadcast via width-16 __shfl (source lanes always in caller's active
// group — round-6 rule). Means (bf16) go to a per-wave LDS tile.
// __syncthreads() between phases: the MFMA phase reads LDS rows written by
// OTHER lanes; without an explicit barrier the compiler's per-thread alias
// analysis may hoist the ds_read above the ds_writes (round-8 NaN bug).
__global__ __launch_bounds__(256) void fused_gather_mfma(
    const unsigned short* __restrict__ feat,   // gather source == root input
    const int* __restrict__ row_start, const int* __restrict__ srcs,
    const unsigned short* __restrict__ Bt, const float* __restrict__ bias,
    const float* __restrict__ g, const float* __restrict__ be,
    const float* __restrict__ m, const float* __restrict__ v,
    unsigned short* __restrict__ outb, int tiles) {
  __shared__ __align__(16) unsigned short s_a[4][16][136];
  int wid = threadIdx.x >> 6, lane = threadIdx.x & 63;
  int tile = blockIdx.x * 4 + wid;
  tile = min(tile, tiles - 1);   // no early return (barrier below); dup writes benign
  int row0 = tile * 16;
  int grp = lane >> 4, s = lane & 15;
  const unsigned short* fp = feat + s * 8;

  // ---- gather phase ----
  for (int n = 0; n < 4; n++) {
    int node = row0 + n * 4 + grp;
    int start = row_start[node], end = row_start[node + 1];
    float a[8];
#pragma unroll
    for (int i = 0; i < 8; i++) a[i] = 0.f;
    for (int base = start; base < end; base += 16) {
      int cnt = min(end - base, 16);           // group-uniform
      int idxv = (base + s < end) ? srcs[base + s] : 0;
      int M = (cnt + 1) >> 1;
      for (int mm = 0; mm < M; mm++) {
        int e0 = mm * 2, e1 = e0 + 1;          // e0 < cnt always
        int s0 = __shfl(idxv, e0, 16);
        int s1 = __shfl(idxv, e1, 16);
        float w1 = (e1 < cnt) ? 1.f : 0.f;
        short8 v0 = *(const short8*)(fp + (long)s0 * D);
        short8 v1 = *(const short8*)(fp + (long)s1 * D);
#pragma unroll
        for (int i = 0; i < 8; i++)
          a[i] += b2f((unsigned short)v0[i]) + w1 * b2f((unsigned short)v1[i]);
      }
    }
    float iv = 1.0f / fmaxf((float)(end - start), 1.0f);
    uint4 p;
    p.x = (unsigned)f2b(a[0] * iv) | ((unsigned)f2b(a[1] * iv) << 16);
    p.y = (unsigned)f2b(a[2] * iv) | ((unsigned)f2b(a[3] * iv) << 16);
    p.z = (unsigned)f2b(a[4] * iv) | ((unsigned)f2b(a[5] * iv) << 16);
    p.w = (unsigned)f2b(a[6] * iv) | ((unsigned)f2b(a[7] * iv) << 16);
    *(uint4*)&s_a[wid][n * 4 + grp][s * 8] = p;
  }

  __syncthreads();  // cross-lane LDS dependency: writes above, reads below

  // ---- mfma phase ----
  int r15 = s, hi = grp;
  f32x4 acc[8];
#pragma unroll
  for (int f = 0; f < 8; f++) acc[f] = (f32x4)(0.f);

  const unsigned short* As = &s_a[wid][r15][hi * 8];
  const unsigned short* Ax = feat + (long)(row0 + r15) * D + hi * 8;
  const unsigned short* Bp = Bt + (long)r15 * 256 + hi * 8;

#pragma unroll
  for (int kf = 0; kf < 8; kf++) {
    const int kk = kf * 32;
    short8 a = (kf < 4) ? *(const short8*)(As + kk)
                        : *(const short8*)(Ax + (kk - 128));
#pragma unroll
    for (int f = 0; f < 8; f++) {
      short8 b = *(const short8*)(Bp + (long)f * 16 * 256 + kk);
      acc[f] = __builtin_amdgcn_mfma_f32_16x16x32_bf16(a, b, acc[f], 0, 0, 0);
    }
  }

#pragma unroll
  for (int f = 0; f < 8; f++) {
    int col = f * 16 + r15;
    float bj = bias[col];
    float sc = g[col] * rsqrtf(v[col] + BN_EPS);
    float sh = be[col] - m[col] * sc;
#pragma unroll
    for (int r = 0; r < 4; r++) {
      int row = row0 + hi * 4 + r;
      float val = fmaxf((acc[f][r] + bj) * sc + sh, 0.f);
      outb[(long)row * D + col] = f2b(val);
    }
  }
}

// ---------------- layer-3 transform: [Z | P] = h @ [W3l | W3r] ----------------
__global__ __launch_bounds__(256) void trans_mfma(
    const unsigned short* __restrict__ xb, const unsigned short* __restrict__ Bt3,
    const float* __restrict__ bias, unsigned short* __restrict__ Z,
    float* __restrict__ outP, int tiles) {
  const int NF = 7;
  int wid = threadIdx.x >> 6, lane = threadIdx.x & 63;
  int tile = blockIdx.x * 4 + wid;
  if (tile >= tiles) return;
  int row0 = tile * 16;
  int r15 = lane & 15, hi = lane >> 4;

  f32x4 acc[NF];
#pragma unroll
  for (int f = 0; f < NF; f++) acc[f] = (f32x4)(0.f);

  const unsigned short* Ar = xb + (long)(row0 + r15) * D + hi * 8;
  const unsigned short* Bp = Bt3 + (long)r15 * 128 + hi * 8;

#pragma unroll
  for (int kf = 0; kf < 4; kf++) {
    const int kk = kf * 32;
    short8 a = *(const short8*)(Ar + kk);
#pragma unroll
    for (int f = 0; f < NF; f++) {
      short8 b = *(const short8*)(Bp + (long)f * 16 * 128 + kk);
      acc[f] = __builtin_amdgcn_mfma_f32_16x16x32_bf16(a, b, acc[f], 0, 0, 0);
    }
  }

#pragma unroll
  for (int f = 0; f < NF; f++) {
    int col = f * 16 + r15;
#pragma unroll
    for (int r = 0; r < 4; r++) {
      int row = row0 + hi * 4 + r;
      float val = acc[f][r];
      if (col < ZW) {
        Z[(long)row * ZW + col] = f2b(val);
      } else {
        int pc = col - 64;
        if (pc < DOUT3) outP[(long)row * DOUT3 + pc] = val + bias[pc];
      }
    }
  }
}

// ------- layer-3 gather: group-per-node, lane s owns cols [4s,4s+4) -------
__global__ __launch_bounds__(256) void gather_add47(const unsigned short* __restrict__ Z,
                                                    const int* __restrict__ row_start,
                                                    const int* __restrict__ srcs,
                                                    float* __restrict__ outP) {
  int t = blockIdx.x * blockDim.x + threadIdx.x;
  int node = t >> 4;
  int s = t & 15;
  if (node >= NN) return;
  int start = row_start[node], end = row_start[node + 1];
  float a[4];
#pragma unroll
  for (int i = 0; i < 4; i++) a[i] = 0.f;
  const unsigned short* zp = Z + s * 4;
  for (int base = start; base < end; base += 16) {
    int cnt = min(end - base, 16);
    int idxv = (base + s < end) ? srcs[base + s] : 0;
    int M = (cnt + 1) >> 1;
    for (int mm = 0; mm < M; mm++) {
      int e0 = mm * 2, e1 = e0 + 1;
      int s0 = __shfl(idxv, e0, 16);
      int s1 = __shfl(idxv, e1, 16);
      float w1 = (e1 < cnt) ? 1.f : 0.f;
      uint2 u0 = *(const uint2*)(zp + (long)s0 * ZW);
      uint2 u1 = *(const uint2*)(zp + (long)s1 * ZW);
      a[0] += b2f((unsigned short)u0.x) + w1 * b2f((unsigned short)u1.x);
      a[1] += b2f((unsigned short)(u0.x >> 16)) + w1 * b2f((unsigned short)(u1.x >> 16));
      a[2] += b2f((unsigned short)u0.y) + w1 * b2f((unsigned short)u1.y);
      a[3] += b2f((unsigned short)(u0.y >> 16)) + w1 * b2f((unsigned short)(u1.y >> 16));
    }
  }
  float iv = 1.0f / fmaxf((float)(end - start), 1.0f);
#pragma unroll
  for (int i = 0; i < 4; i++) {
    int c = s * 4 + i;
    if (c < DOUT3) {
      long o = (long)node * DOUT3 + c;
      outP[o] = outP[o] + a[i] * iv;
    }
  }
}

extern "C" void kernel_launch(void* const* d_in, const int* in_sizes, int n_in,
                              void* d_out, int out_size, void* d_ws, size_t ws_size,
                              hipStream_t stream) {
  const float* x = (const float*)d_in[0];
  const int* ei = (const int*)d_in[1];
  const int* src = ei;
  const int* dst = ei + NE;
  const float* W1l = (const float*)d_in[2];
  const float* b1  = (const float*)d_in[3];
  const float* W1r = (const float*)d_in[4];
  const float* W2l = (const float*)d_in[5];
  const float* b2  = (const float*)d_in[6];
  const float* W2r = (const float*)d_in[7];
  const float* W3l = (const float*)d_in[8];
  const float* b3  = (const float*)d_in[9];
  const float* W3r = (const float*)d_in[10];
  const float* g1  = (const float*)d_in[11];
  const float* be1 = (const float*)d_in[12];
  const float* m1  = (const float*)d_in[13];
  const float* v1  = (const float*)d_in[14];
  const float* g2  = (const float*)d_in[15];
  const float* be2 = (const float*)d_in[16];
  const float* m2  = (const float*)d_in[17];
  const float* v2  = (const float*)d_in[18];

  float* out = (float*)d_out;

  // ---- workspace layout ----
  int* deg       = (int*)d_ws;                 // NN
  int* row_start = deg + NN;                   // NN+4
  int* cursor    = row_start + NN + 4;         // NN
  int* partials  = cursor + NN;                // 256
  int* srcs      = partials + 256;             // NE
  unsigned short* xb   = (unsigned short*)(srcs + NE);   // NN*D
  unsigned short* h2b  = xb + (long)NN * D;              // NN*D (layer-2 out)
  unsigned short* h1b  = h2b + (long)NN * D;             // NN*D (layer-1 out)
  unsigned short* Zb   = h1b + (long)NN * D;             // NN*ZW
  unsigned short* Bt1  = Zb + (long)NN * ZW;             // 128*256
  unsigned short* Bt2  = Bt1 + 128 * 256;                // 128*256
  unsigned short* Bt3  = Bt2 + 128 * 256;                // 112*128

  // ---- prep: zero deg, then merged conversions + histogram ----
  zero_int<<<SB, 256, 0, stream>>>(deg, NN);
  prep_hist<<<3680, 256, 0, stream>>>(
      (const float4*)x, xb, W1l, W1r, Bt1, W2l, W2r, Bt2, W3l, W3r, Bt3, dst, deg);

  // ---- CSR scan + build ----
  scan_local<<<SB, NPB, 0, stream>>>(deg, row_start, partials);
  scan_add<<<SB, NPB, 0, stream>>>(row_start, partials, cursor);
  build_kernel<<<(NE + 255) / 256, 256, 0, stream>>>(src, dst, cursor, srcs, NE);

  int tiles = NN / 16;                   // 3125
  int lblocks = (tiles + 3) / 4;         // 782

  // ---- layer 1: fused gather(xb) + GEMM -> h1b ----
  fused_gather_mfma<<<lblocks, 256, 0, stream>>>(
      xb, row_start, srcs, Bt1, b1, g1, be1, m1, v1, h1b, tiles);

  // ---- layer 2: fused gather(h1b) + GEMM -> h2b (no aliasing) ----
  fused_gather_mfma<<<lblocks, 256, 0, stream>>>(
      h1b, row_start, srcs, Bt2, b2, g2, be2, m2, v2, h2b, tiles);

  // ---- layer 3: transform then 47-wide gather-add ----
  trans_mfma<<<lblocks, 256, 0, stream>>>(h2b, Bt3, b3, Zb, out, tiles);
  gather_add47<<<(NN * 16 + 255) / 256, 256, 0, stream>>>(Zb, row_start, srcs, out);
}

// Round 10
// 222.580 us; speedup vs baseline: 14.8096x; 1.0654x over previous
//
#include <hip/hip_runtime.h>

#define NN 50000
#define NE 600000
#define D 128
#define DOUT3 47
#define ZW 64   // padded Z width (bf16) for layer-3 gather
#define BN_EPS 1e-5f
#define NPB 256
#define SB 196  // scan blocks = ceil(NN/NPB)

typedef __attribute__((ext_vector_type(8))) short short8;
typedef __attribute__((ext_vector_type(4))) float f32x4;

__device__ inline unsigned short f2b(float f) {
  union { float f; unsigned u; } c; c.f = f;
  unsigned u = c.u;
  unsigned r = (u + 0x7FFFu + ((u >> 16) & 1u)) >> 16;
  return (unsigned short)r;
}
__device__ inline float b2f(unsigned short h) {
  union { unsigned u; float f; } c; c.u = ((unsigned)h) << 16;
  return c.f;
}

// ---------------- zero deg (must precede prep_hist's atomics) ----------------
__global__ void zero_int(int* __restrict__ p, int n) {
  int i = blockIdx.x * blockDim.x + threadIdx.x;
  if (i < n) p[i] = 0;
}

// ------- merged prep+hist: conv_bf16 | Bt1 | Bt2 | Bt3 | hist atomics -------
// block ranges: [0,1024) conv x; [1024,1152) Bt1; [1152,1280) Bt2;
// [1280,1336) Bt3; [1336,3680) hist.
__global__ __launch_bounds__(256) void prep_hist(
    const float4* __restrict__ x4, unsigned short* __restrict__ xb,
    const float* __restrict__ W1l, const float* __restrict__ W1r, unsigned short* __restrict__ Bt1,
    const float* __restrict__ W2l, const float* __restrict__ W2r, unsigned short* __restrict__ Bt2,
    const float* __restrict__ W3l, const float* __restrict__ W3r, unsigned short* __restrict__ Bt3,
    const int* __restrict__ dst, int* __restrict__ deg) {
  int b = blockIdx.x;
  int t = threadIdx.x;
  if (b < 1024) {
    long n4 = (long)NN * D / 4;
    for (long i = (long)b * 256 + t; i < n4; i += 1024L * 256) {
      float4 v = x4[i];
      uint2 p;
      p.x = (unsigned)f2b(v.x) | ((unsigned)f2b(v.y) << 16);
      p.y = (unsigned)f2b(v.z) | ((unsigned)f2b(v.w) << 16);
      *(uint2*)(xb + i * 4) = p;
    }
  } else if (b < 1280) {
    const float* Wl = (b < 1152) ? W1l : W2l;
    const float* Wr = (b < 1152) ? W1r : W2r;
    unsigned short* Bt = (b < 1152) ? Bt1 : Bt2;
    int idx = ((b < 1152) ? (b - 1024) : (b - 1152)) * 256 + t;
    int j = idx >> 8, k = idx & 255;
    float v = (k < 128) ? Wl[k * D + j] : Wr[(k - 128) * D + j];
    Bt[idx] = f2b(v);
  } else if (b < 1336) {
    int idx = (b - 1280) * 256 + t;
    if (idx < 112 * 128) {
      int j = idx >> 7, k = idx & 127;
      float v = 0.f;
      if (j < DOUT3) v = W3l[k * DOUT3 + j];
      else if (j >= 64 && j < 64 + DOUT3) v = W3r[k * DOUT3 + (j - 64)];
      Bt3[idx] = f2b(v);
    }
  } else {
    int e = (b - 1336) * 256 + t;
    if (e < NE) {
      int d = dst[e];
      d = max(0, min(NN - 1, d));
      atomicAdd(&deg[d], 1);
    }
  }
}

// ---------------- CSR scan + build ----------------
__global__ __launch_bounds__(NPB) void scan_local(const int* __restrict__ deg,
                                                  int* __restrict__ row_start,
                                                  int* __restrict__ partials) {
  __shared__ int s[NPB];
  int t = threadIdx.x;
  int i = blockIdx.x * NPB + t;
  int v = (i < NN) ? deg[i] : 0;
  s[t] = v;
  __syncthreads();
  for (int off = 1; off < NPB; off <<= 1) {
    int u = (t >= off) ? s[t - off] : 0;
    __syncthreads();
    s[t] += u;
    __syncthreads();
  }
  if (i < NN) row_start[i] = s[t] - v;
  if (t == NPB - 1) partials[blockIdx.x] = s[NPB - 1];
}

__global__ __launch_bounds__(NPB) void scan_add(int* __restrict__ row_start,
                                                const int* __restrict__ partials,
                                                int* __restrict__ cursor) {
  __shared__ int s[NPB];
  int t = threadIdx.x;
  int v = (t < SB) ? partials[t] : 0;
  s[t] = v;
  __syncthreads();
  for (int off = 1; off < NPB; off <<= 1) {
    int u = (t >= off) ? s[t - off] : 0;
    __syncthreads();
    s[t] += u;
    __syncthreads();
  }
  int base = s[blockIdx.x] - partials[blockIdx.x];
  int i = blockIdx.x * NPB + t;
  if (i < NN) {
    int r = row_start[i] + base;
    row_start[i] = r;
    cursor[i] = r;
  }
  if (i == 0) row_start[NN] = NE;
}

__global__ void build_kernel(const int* __restrict__ src, const int* __restrict__ dst,
                             int* __restrict__ cursor, int* __restrict__ srcs, int E) {
  int e = blockIdx.x * blockDim.x + threadIdx.x;
  if (e < E) {
    int d = dst[e];
    d = max(0, min(NN - 1, d));
    int s = src[e];
    s = max(0, min(NN - 1, s));
    int pos = atomicAdd(&cursor[d], 1);
    srcs[pos] = s;
  }
}

// ---------------- fused gather + MFMA layer (layers 1-2) ----------------
// ONE WAVE per 16-row tile, 1 wave per block (wave-local barrier, independent
// scheduling so MFMA of some waves overlaps gather loads of others).
// Gather: each 16-lane group owns one node per round (4 rounds); lane s
// accumulates cols [8s,8s+8); 4 edges in flight per iteration (4-deep ILP).
// Index broadcast via width-16 __shfl (source lanes always in caller's active
// group — round-6 rule). __syncthreads() between phases (round-8 rule: MFMA
// reads LDS rows written by other lanes).
__global__ __launch_bounds__(64) void fused_gather_mfma(
    const unsigned short* __restrict__ feat,   // gather source == root input
    const int* __restrict__ row_start, const int* __restrict__ srcs,
    const unsigned short* __restrict__ Bt, const float* __restrict__ bias,
    const float* __restrict__ g, const float* __restrict__ be,
    const float* __restrict__ m, const float* __restrict__ v,
    unsigned short* __restrict__ outb) {
  __shared__ __align__(16) unsigned short s_a[16][136];
  int lane = threadIdx.x;
  int tile = blockIdx.x;
  int row0 = tile * 16;
  int grp = lane >> 4, s = lane & 15;
  const unsigned short* fp = feat + s * 8;

  // ---- gather phase ----
  for (int n = 0; n < 4; n++) {
    int node = row0 + n * 4 + grp;
    int start = row_start[node], end = row_start[node + 1];
    float a[8];
#pragma unroll
    for (int i = 0; i < 8; i++) a[i] = 0.f;
    for (int base = start; base < end; base += 16) {
      int cnt = min(end - base, 16);           // group-uniform
      int idxv = (base + s < end) ? srcs[base + s] : 0;
      int M = (cnt + 3) >> 2;                  // quads
      for (int q = 0; q < M; q++) {
        int e0 = q * 4;
        int s0 = __shfl(idxv, e0, 16);
        int s1 = __shfl(idxv, e0 + 1, 16);
        int s2 = __shfl(idxv, e0 + 2, 16);
        int s3 = __shfl(idxv, e0 + 3, 16);
        float w1 = (e0 + 1 < cnt) ? 1.f : 0.f;
        float w2 = (e0 + 2 < cnt) ? 1.f : 0.f;
        float w3 = (e0 + 3 < cnt) ? 1.f : 0.f;
        short8 v0 = *(const short8*)(fp + (long)s0 * D);
        short8 v1 = *(const short8*)(fp + (long)s1 * D);
        short8 v2 = *(const short8*)(fp + (long)s2 * D);
        short8 v3 = *(const short8*)(fp + (long)s3 * D);
#pragma unroll
        for (int i = 0; i < 8; i++)
          a[i] += (b2f((unsigned short)v0[i]) + w1 * b2f((unsigned short)v1[i])) +
                  (w2 * b2f((unsigned short)v2[i]) + w3 * b2f((unsigned short)v3[i]));
      }
    }
    float iv = 1.0f / fmaxf((float)(end - start), 1.0f);
    uint4 p;
    p.x = (unsigned)f2b(a[0] * iv) | ((unsigned)f2b(a[1] * iv) << 16);
    p.y = (unsigned)f2b(a[2] * iv) | ((unsigned)f2b(a[3] * iv) << 16);
    p.z = (unsigned)f2b(a[4] * iv) | ((unsigned)f2b(a[5] * iv) << 16);
    p.w = (unsigned)f2b(a[6] * iv) | ((unsigned)f2b(a[7] * iv) << 16);
    *(uint4*)&s_a[n * 4 + grp][s * 8] = p;
  }

  __syncthreads();  // cross-lane LDS dependency (wave-local barrier)

  // ---- mfma phase ----
  int r15 = s, hi = grp;
  f32x4 acc[8];
#pragma unroll
  for (int f = 0; f < 8; f++) acc[f] = (f32x4)(0.f);

  const unsigned short* As = &s_a[r15][hi * 8];
  const unsigned short* Ax = feat + (long)(row0 + r15) * D + hi * 8;
  const unsigned short* Bp = Bt + (long)r15 * 256 + hi * 8;

#pragma unroll
  for (int kf = 0; kf < 8; kf++) {
    const int kk = kf * 32;
    short8 a = (kf < 4) ? *(const short8*)(As + kk)
                        : *(const short8*)(Ax + (kk - 128));
#pragma unroll
    for (int f = 0; f < 8; f++) {
      short8 b = *(const short8*)(Bp + (long)f * 16 * 256 + kk);
      acc[f] = __builtin_amdgcn_mfma_f32_16x16x32_bf16(a, b, acc[f], 0, 0, 0);
    }
  }

#pragma unroll
  for (int f = 0; f < 8; f++) {
    int col = f * 16 + r15;
    float bj = bias[col];
    float sc = g[col] * rsqrtf(v[col] + BN_EPS);
    float sh = be[col] - m[col] * sc;
#pragma unroll
    for (int r = 0; r < 4; r++) {
      int row = row0 + hi * 4 + r;
      float val = fmaxf((acc[f][r] + bj) * sc + sh, 0.f);
      outb[(long)row * D + col] = f2b(val);
    }
  }
}

// ---------------- layer-3 transform: [Z | P] = h @ [W3l | W3r] ----------------
__global__ __launch_bounds__(256) void trans_mfma(
    const unsigned short* __restrict__ xb, const unsigned short* __restrict__ Bt3,
    const float* __restrict__ bias, unsigned short* __restrict__ Z,
    float* __restrict__ outP, int tiles) {
  const int NF = 7;
  int wid = threadIdx.x >> 6, lane = threadIdx.x & 63;
  int tile = blockIdx.x * 4 + wid;
  if (tile >= tiles) return;
  int row0 = tile * 16;
  int r15 = lane & 15, hi = lane >> 4;

  f32x4 acc[NF];
#pragma unroll
  for (int f = 0; f < NF; f++) acc[f] = (f32x4)(0.f);

  const unsigned short* Ar = xb + (long)(row0 + r15) * D + hi * 8;
  const unsigned short* Bp = Bt3 + (long)r15 * 128 + hi * 8;

#pragma unroll
  for (int kf = 0; kf < 4; kf++) {
    const int kk = kf * 32;
    short8 a = *(const short8*)(Ar + kk);
#pragma unroll
    for (int f = 0; f < NF; f++) {
      short8 b = *(const short8*)(Bp + (long)f * 16 * 128 + kk);
      acc[f] = __builtin_amdgcn_mfma_f32_16x16x32_bf16(a, b, acc[f], 0, 0, 0);
    }
  }

#pragma unroll
  for (int f = 0; f < NF; f++) {
    int col = f * 16 + r15;
#pragma unroll
    for (int r = 0; r < 4; r++) {
      int row = row0 + hi * 4 + r;
      float val = acc[f][r];
      if (col < ZW) {
        Z[(long)row * ZW + col] = f2b(val);
      } else {
        int pc = col - 64;
        if (pc < DOUT3) outP[(long)row * DOUT3 + pc] = val + bias[pc];
      }
    }
  }
}

// ------- layer-3 gather: group-per-node, lane s owns cols [4s,4s+4), 4-deep ILP -------
__global__ __launch_bounds__(256) void gather_add47(const unsigned short* __restrict__ Z,
                                                    const int* __restrict__ row_start,
                                                    const int* __restrict__ srcs,
                                                    float* __restrict__ outP) {
  int t = blockIdx.x * blockDim.x + threadIdx.x;
  int node = t >> 4;
  int s = t & 15;
  if (node >= NN) return;
  int start = row_start[node], end = row_start[node + 1];
  float a[4];
#pragma unroll
  for (int i = 0; i < 4; i++) a[i] = 0.f;
  const unsigned short* zp = Z + s * 4;
  for (int base = start; base < end; base += 16) {
    int cnt = min(end - base, 16);
    int idxv = (base + s < end) ? srcs[base + s] : 0;
    int M = (cnt + 3) >> 2;
    for (int q = 0; q < M; q++) {
      int e0 = q * 4;
      int s0 = __shfl(idxv, e0, 16);
      int s1 = __shfl(idxv, e0 + 1, 16);
      int s2 = __shfl(idxv, e0 + 2, 16);
      int s3 = __shfl(idxv, e0 + 3, 16);
      float w1 = (e0 + 1 < cnt) ? 1.f : 0.f;
      float w2 = (e0 + 2 < cnt) ? 1.f : 0.f;
      float w3 = (e0 + 3 < cnt) ? 1.f : 0.f;
      uint2 u0 = *(const uint2*)(zp + (long)s0 * ZW);
      uint2 u1 = *(const uint2*)(zp + (long)s1 * ZW);
      uint2 u2 = *(const uint2*)(zp + (long)s2 * ZW);
      uint2 u3 = *(const uint2*)(zp + (long)s3 * ZW);
      a[0] += (b2f((unsigned short)u0.x) + w1 * b2f((unsigned short)u1.x)) +
              (w2 * b2f((unsigned short)u2.x) + w3 * b2f((unsigned short)u3.x));
      a[1] += (b2f((unsigned short)(u0.x >> 16)) + w1 * b2f((unsigned short)(u1.x >> 16))) +
              (w2 * b2f((unsigned short)(u2.x >> 16)) + w3 * b2f((unsigned short)(u3.x >> 16)));
      a[2] += (b2f((unsigned short)u0.y) + w1 * b2f((unsigned short)u1.y)) +
              (w2 * b2f((unsigned short)u2.y) + w3 * b2f((unsigned short)u3.y));
      a[3] += (b2f((unsigned short)(u0.y >> 16)) + w1 * b2f((unsigned short)(u1.y >> 16))) +
              (w2 * b2f((unsigned short)(u2.y >> 16)) + w3 * b2f((unsigned short)(u3.y >> 16)));
    }
  }
  float iv = 1.0f / fmaxf((float)(end - start), 1.0f);
#pragma unroll
  for (int i = 0; i < 4; i++) {
    int c = s * 4 + i;
    if (c < DOUT3) {
      long o = (long)node * DOUT3 + c;
      outP[o] = outP[o] + a[i] * iv;
    }
  }
}

extern "C" void kernel_launch(void* const* d_in, const int* in_sizes, int n_in,
                              void* d_out, int out_size, void* d_ws, size_t ws_size,
                              hipStream_t stream) {
  const float* x = (const float*)d_in[0];
  const int* ei = (const int*)d_in[1];
  const int* src = ei;
  const int* dst = ei + NE;
  const float* W1l = (const float*)d_in[2];
  const float* b1  = (const float*)d_in[3];
  const float* W1r = (const float*)d_in[4];
  const float* W2l = (const float*)d_in[5];
  const float* b2  = (const float*)d_in[6];
  const float* W2r = (const float*)d_in[7];
  const float* W3l = (const float*)d_in[8];
  const float* b3  = (const float*)d_in[9];
  const float* W3r = (const float*)d_in[10];
  const float* g1  = (const float*)d_in[11];
  const float* be1 = (const float*)d_in[12];
  const float* m1  = (const float*)d_in[13];
  const float* v1  = (const float*)d_in[14];
  const float* g2  = (const float*)d_in[15];
  const float* be2 = (const float*)d_in[16];
  const float* m2  = (const float*)d_in[17];
  const float* v2  = (const float*)d_in[18];

  float* out = (float*)d_out;

  // ---- workspace layout ----
  int* deg       = (int*)d_ws;                 // NN
  int* row_start = deg + NN;                   // NN+4
  int* cursor    = row_start + NN + 4;         // NN
  int* partials  = cursor + NN;                // 256
  int* srcs      = partials + 256;             // NE
  unsigned short* xb   = (unsigned short*)(srcs + NE);   // NN*D
  unsigned short* h2b  = xb + (long)NN * D;              // NN*D (layer-2 out)
  unsigned short* h1b  = h2b + (long)NN * D;             // NN*D (layer-1 out)
  unsigned short* Zb   = h1b + (long)NN * D;             // NN*ZW
  unsigned short* Bt1  = Zb + (long)NN * ZW;             // 128*256
  unsigned short* Bt2  = Bt1 + 128 * 256;                // 128*256
  unsigned short* Bt3  = Bt2 + 128 * 256;                // 112*128

  // ---- prep: zero deg, then merged conversions + histogram ----
  zero_int<<<SB, 256, 0, stream>>>(deg, NN);
  prep_hist<<<3680, 256, 0, stream>>>(
      (const float4*)x, xb, W1l, W1r, Bt1, W2l, W2r, Bt2, W3l, W3r, Bt3, dst, deg);

  // ---- CSR scan + build ----
  scan_local<<<SB, NPB, 0, stream>>>(deg, row_start, partials);
  scan_add<<<SB, NPB, 0, stream>>>(row_start, partials, cursor);
  build_kernel<<<(NE + 255) / 256, 256, 0, stream>>>(src, dst, cursor, srcs, NE);

  int tiles = NN / 16;                   // 3125

  // ---- layer 1: fused gather(xb) + GEMM -> h1b (1 wave/block) ----
  fused_gather_mfma<<<tiles, 64, 0, stream>>>(
      xb, row_start, srcs, Bt1, b1, g1, be1, m1, v1, h1b);

  // ---- layer 2: fused gather(h1b) + GEMM -> h2b (no aliasing) ----
  fused_gather_mfma<<<tiles, 64, 0, stream>>>(
      h1b, row_start, srcs, Bt2, b2, g2, be2, m2, v2, h2b);

  // ---- layer 3: transform then 47-wide gather-add ----
  trans_mfma<<<(tiles + 3) / 4, 256, 0, stream>>>(h2b, Bt3, b3, Zb, out, tiles);
  gather_add47<<<(NN * 16 + 255) / 256, 256, 0, stream>>>(Zb, row_start, srcs, out);
}